// Round 1
// baseline (442.439 us; speedup 1.0000x reference)
//
#include <hip/hip_runtime.h>

#define DEV_INLINE __device__ __forceinline__

constexpr int BATCH = 2;
constexpr int HH = 96, WW = 96, CC = 96;
constexpr int DI = 192;            // d_inner == d_model for mamba
constexpr int NS = 16;             // d_state
constexpr int LSEQ = HH * WW;      // 9216
constexpr int TT = BATCH * LSEQ;   // 18432 tokens
constexpr int CHUNK = 96;          // scan chunk length
constexpr int NCHUNK = LSEQ / CHUNK; // 96 chunks per batch
constexpr int QDN = DI * NS;       // 3072

DEV_INLINE float silu_f(float x) { return x / (1.f + __expf(-x)); }
DEV_INLINE float softplus_f(float x) {
  // stable log(1+exp(x)) = max(x,0) + log1p(exp(-|x|))
  return fmaxf(x, 0.f) + log1pf(__expf(-fabsf(x)));
}

// ---------------- LayerNorm over C=96, one wave per token ----------------
__global__ __launch_bounds__(256)
void ln_kernel(const float* __restrict__ x, const float* __restrict__ w,
               const float* __restrict__ bb, float* __restrict__ xn)
{
  int wid = (blockIdx.x * blockDim.x + threadIdx.x) >> 6;  // token
  int lane = threadIdx.x & 63;
  if (wid >= TT) return;
  const float* xr = x + (size_t)wid * CC;
  float v0 = xr[lane];
  float v1 = (lane < 32) ? xr[64 + lane] : 0.f;
  float s = v0 + v1, ss = v0 * v0 + v1 * v1;
#pragma unroll
  for (int off = 32; off >= 1; off >>= 1) {
    s  += __shfl_xor(s, off);
    ss += __shfl_xor(ss, off);
  }
  float mean = s * (1.f / 96.f);
  float var  = ss * (1.f / 96.f) - mean * mean;
  float rstd = rsqrtf(var + 1e-5f);
  float* o = xn + (size_t)wid * CC;
  o[lane] = (v0 - mean) * rstd * w[lane] + bb[lane];
  if (lane < 32) o[64 + lane] = (v1 - mean) * rstd * w[64 + lane] + bb[64 + lane];
}

// ---------------- generic fp32 GEMM: C[M,N] = A[M,K] @ B[K,N] ----------------
// BM=128, BN=64, BK=16, 256 threads, 8x4 per thread.
// EPI: 0 none, 1 mul by silu(aux[row,col]), 2 add aux[row,col] (residual)
template<int EPI>
__global__ __launch_bounds__(256)
void gemm_kernel(const float* __restrict__ A, int lda,
                 const float* __restrict__ B, int ldb,
                 float* __restrict__ C, int ldc,
                 int N, int K,
                 const float* __restrict__ aux, int ldaux)
{
  __shared__ __align__(16) float As[16][132];  // [k][m], +4 pad
  __shared__ __align__(16) float Bs[16][64];   // [k][n]
  const int tid = threadIdx.x;
  const int tx = tid & 15;          // n-group
  const int ty = tid >> 4;          // m-group
  const int m0 = blockIdx.x * 128;
  const int n0 = blockIdx.y * 64;
  const int arow = tid >> 2;        // 0..63
  const int akq  = (tid & 3) << 2;  // 0,4,8,12
  const int brow = tid >> 4;        // 0..15
  const int bcol = (tid & 15) << 2; // 0..60

  float acc[8][4];
#pragma unroll
  for (int i = 0; i < 8; ++i)
#pragma unroll
    for (int j = 0; j < 4; ++j) acc[i][j] = 0.f;

  for (int k0 = 0; k0 < K; k0 += 16) {
    float4 a0 = *(const float4*)(A + (size_t)(m0 + arow) * lda + (k0 + akq));
    float4 a1 = *(const float4*)(A + (size_t)(m0 + arow + 64) * lda + (k0 + akq));
    float4 bv = make_float4(0.f, 0.f, 0.f, 0.f);
    if (n0 + bcol < N)
      bv = *(const float4*)(B + (size_t)(k0 + brow) * ldb + (n0 + bcol));
    __syncthreads();
    As[akq + 0][arow] = a0.x;
    As[akq + 1][arow] = a0.y;
    As[akq + 2][arow] = a0.z;
    As[akq + 3][arow] = a0.w;
    As[akq + 0][arow + 64] = a1.x;
    As[akq + 1][arow + 64] = a1.y;
    As[akq + 2][arow + 64] = a1.z;
    As[akq + 3][arow + 64] = a1.w;
    *(float4*)&Bs[brow][bcol] = bv;
    __syncthreads();
#pragma unroll
    for (int k = 0; k < 16; ++k) {
      float4 av0 = *(const float4*)&As[k][ty * 8];
      float4 av1 = *(const float4*)&As[k][ty * 8 + 4];
      float4 bv0 = *(const float4*)&Bs[k][tx * 4];
      float am[8] = {av0.x, av0.y, av0.z, av0.w, av1.x, av1.y, av1.z, av1.w};
      float bn[4] = {bv0.x, bv0.y, bv0.z, bv0.w};
#pragma unroll
      for (int i = 0; i < 8; ++i)
#pragma unroll
        for (int j = 0; j < 4; ++j)
          acc[i][j] = fmaf(am[i], bn[j], acc[i][j]);
    }
  }

  const int col = n0 + tx * 4;
  if (col < N) {
#pragma unroll
    for (int i = 0; i < 8; ++i) {
      const int row = m0 + ty * 8 + i;
      float4 v = make_float4(acc[i][0], acc[i][1], acc[i][2], acc[i][3]);
      if (EPI == 1) {
        const float4 g = *(const float4*)(aux + (size_t)row * ldaux + col);
        v.x *= silu_f(g.x); v.y *= silu_f(g.y); v.z *= silu_f(g.z); v.w *= silu_f(g.w);
      } else if (EPI == 2) {
        const float4 r = *(const float4*)(aux + (size_t)row * ldaux + col);
        v.x += r.x; v.y += r.y; v.z += r.z; v.w += r.w;
      }
      *(float4*)(C + (size_t)row * ldc + col) = v;
    }
  }
}

// ---------------- depthwise 3x3 conv + SiLU (channels-last) ----------------
// input: xz0 cols [0,192) with ld=384; output xc (TT,192)
__global__ __launch_bounds__(256)
void conv2d_silu_kernel(const float* __restrict__ xz0, const float* __restrict__ w,
                        float* __restrict__ xc)
{
  __shared__ float ws[DI * 9];
  for (int i = threadIdx.x; i < DI * 9; i += 256) ws[i] = w[i];
  __syncthreads();
  int id = blockIdx.x * 256 + threadIdx.x;     // TT*48
  int dq = id % 48;
  int p  = id / 48;
  int j = p % WW;
  int i = (p / WW) % HH;
  int b = p / (WW * HH);
  int d = dq * 4;
  float a0 = 0.f, a1 = 0.f, a2 = 0.f, a3 = 0.f;
#pragma unroll
  for (int ki = 0; ki < 3; ++ki) {
    int ii = i + ki - 1;
    if (ii < 0 || ii >= HH) continue;
#pragma unroll
    for (int kj = 0; kj < 3; ++kj) {
      int jj = j + kj - 1;
      if (jj < 0 || jj >= WW) continue;
      const float4 v = *(const float4*)(xz0 + ((size_t)((b * HH + ii) * WW + jj)) * 384 + d);
      int wk = ki * 3 + kj;
      a0 = fmaf(v.x, ws[(d + 0) * 9 + wk], a0);
      a1 = fmaf(v.y, ws[(d + 1) * 9 + wk], a1);
      a2 = fmaf(v.z, ws[(d + 2) * 9 + wk], a2);
      a3 = fmaf(v.w, ws[(d + 3) * 9 + wk], a3);
    }
  }
  float4 o = make_float4(silu_f(a0), silu_f(a1), silu_f(a2), silu_f(a3));
  *(float4*)(xc + (size_t)p * DI + d) = o;
}

// ---------------- causal depthwise conv1d (k=3) + bias + SiLU ----------------
// input: xz1 cols [0,192) ld=384; output xm (TT,192)
__global__ __launch_bounds__(256)
void conv1d_silu_kernel(const float* __restrict__ xz1, const float* __restrict__ w,
                        const float* __restrict__ bias, float* __restrict__ xm)
{
  int id = blockIdx.x * 256 + threadIdx.x;   // TT*48
  int dq = id % 48;
  int t  = id / 48;
  int l  = t % LSEQ;
  int d  = dq * 4;
  float a0 = bias[d + 0], a1 = bias[d + 1], a2 = bias[d + 2], a3 = bias[d + 3];
#pragma unroll
  for (int k = 0; k < 3; ++k) {
    int ll = l + k - 2;
    if (ll < 0) continue;
    const float4 v = *(const float4*)(xz1 + (size_t)(t + k - 2) * 384 + d);
    a0 = fmaf(v.x, w[(d + 0) * 3 + k], a0);
    a1 = fmaf(v.y, w[(d + 1) * 3 + k], a1);
    a2 = fmaf(v.z, w[(d + 2) * 3 + k], a2);
    a3 = fmaf(v.w, w[(d + 3) * 3 + k], a3);
  }
  float4 o = make_float4(silu_f(a0), silu_f(a1), silu_f(a2), silu_f(a3));
  *(float4*)(xm + (size_t)t * DI + d) = o;
}

// ---------------- dt projection (K=12) + softplus -> delta (TT,192) ----------------
__global__ __launch_bounds__(256)
void dtproj_kernel(const float* __restrict__ xdbl, const float* __restrict__ Wdt,
                   const float* __restrict__ bdt, float* __restrict__ delta)
{
  int id = blockIdx.x * 256 + threadIdx.x;  // TT*192
  int d = id % DI;
  int t = id / DI;
  float acc = bdt[d];
#pragma unroll
  for (int r = 0; r < 12; ++r)
    acc = fmaf(xdbl[(size_t)t * 44 + r], Wdt[r * DI + d], acc);
  delta[id] = softplus_f(acc);
}

// ---------------- selective scan, 3-phase chunked ----------------
// thread id -> (b, g, d, n); lane layout: 4 d-groups x 16 n per wave
__global__ __launch_bounds__(256)
void scan_phase1_kernel(const float* __restrict__ delta, const float* __restrict__ xm,
                        const float* __restrict__ xdbl, const float* __restrict__ Alog,
                        float* __restrict__ P, float* __restrict__ E)
{
  int id = blockIdx.x * 256 + threadIdx.x;   // BATCH*NCHUNK*QDN
  int q = id % QDN;
  int g = (id / QDN) % NCHUNK;
  int b = id / (QDN * NCHUNK);
  int d = q >> 4;
  int n = q & 15;
  float Av = -__expf(Alog[d * NS + n]);
  float p = 1.f, e = 0.f;
  int t0 = b * LSEQ + g * CHUNK;
  for (int l = 0; l < CHUNK; ++l) {
    int t = t0 + l;
    float dl = delta[(size_t)t * DI + d];
    float u  = xm[(size_t)t * DI + d];
    float Bv = xdbl[(size_t)t * 44 + 12 + n];
    float a = __expf(dl * Av);
    p *= a;
    e = fmaf(a, e, dl * u * Bv);
  }
  P[id] = p;
  E[id] = e;
}

__global__ __launch_bounds__(256)
void scan_phase2_kernel(const float* __restrict__ P, const float* __restrict__ E,
                        float* __restrict__ Hin)
{
  int id = blockIdx.x * 256 + threadIdx.x;   // BATCH*QDN = 6144
  int q = id % QDN;
  int b = id / QDN;
  float carry = 0.f;
  for (int g = 0; g < NCHUNK; ++g) {
    int idx = (b * NCHUNK + g) * QDN + q;
    Hin[idx] = carry;
    carry = fmaf(P[idx], carry, E[idx]);
  }
}

// phase3: replay chunk from Hin, emit y = (sum_n h*C + u*D) * silu(z)
__global__ __launch_bounds__(256)
void scan_phase3_kernel(const float* __restrict__ delta, const float* __restrict__ xm,
                        const float* __restrict__ xdbl, const float* __restrict__ Alog,
                        const float* __restrict__ Dv, const float* __restrict__ xz1,
                        const float* __restrict__ Hin, float* __restrict__ yout)
{
  int id = blockIdx.x * 256 + threadIdx.x;
  int q = id % QDN;
  int g = (id / QDN) % NCHUNK;
  int b = id / (QDN * NCHUNK);
  int d = q >> 4;
  int n = q & 15;
  float Av = -__expf(Alog[d * NS + n]);
  float Dd = Dv[d];
  float h = Hin[id];
  int t0 = b * LSEQ + g * CHUNK;
  for (int l = 0; l < CHUNK; ++l) {
    int t = t0 + l;
    float dl = delta[(size_t)t * DI + d];
    float u  = xm[(size_t)t * DI + d];
    float Bv = xdbl[(size_t)t * 44 + 12 + n];
    float Cv = xdbl[(size_t)t * 44 + 28 + n];
    float a = __expf(dl * Av);
    h = fmaf(a, h, dl * u * Bv);
    float yp = h * Cv;
    yp += __shfl_xor(yp, 8, 16);
    yp += __shfl_xor(yp, 4, 16);
    yp += __shfl_xor(yp, 2, 16);
    yp += __shfl_xor(yp, 1, 16);
    if (n == 0) {
      float zv = xz1[(size_t)t * 384 + 192 + d];
      yout[(size_t)t * DI + d] = (yp + u * Dd) * silu_f(zv);
    }
  }
}

// ---------------- launch ----------------
extern "C" void kernel_launch(void* const* d_in, const int* in_sizes, int n_in,
                              void* d_out, int out_size, void* d_ws, size_t ws_size,
                              hipStream_t stream)
{
  const float* x         = (const float*)d_in[0];
  const float* norm_w    = (const float*)d_in[1];
  const float* norm_b    = (const float*)d_in[2];
  const float* in_proj_w = (const float*)d_in[3];
  const float* conv2d_w  = (const float*)d_in[4];
  const float* m_in_proj = (const float*)d_in[5];
  const float* m_c1d_w   = (const float*)d_in[6];
  const float* m_c1d_b   = (const float*)d_in[7];
  const float* m_x_proj  = (const float*)d_in[8];
  const float* m_dt_w    = (const float*)d_in[9];
  const float* m_dt_b    = (const float*)d_in[10];
  const float* m_A_log   = (const float*)d_in[11];
  const float* m_D       = (const float*)d_in[12];
  const float* m_out_w   = (const float*)d_in[13];
  const float* out_w     = (const float*)d_in[14];
  float* out = (float*)d_out;

  float* p = (float*)d_ws;
  float* xn   = p; p += (size_t)TT * 96;
  float* xz0  = p; p += (size_t)TT * 384;   // x_in | x_gate
  float* xc   = p; p += (size_t)TT * 192;
  float* xz1  = p; p += (size_t)TT * 384;   // xm_pre | z
  float* xmb  = p; p += (size_t)TT * 192;
  float* xdbl = p; p += (size_t)TT * 44;    // dt | B | C
  float* dlt  = p; p += (size_t)TT * 192;
  float* Pb   = p; p += (size_t)BATCH * NCHUNK * QDN;
  float* Eb   = p; p += (size_t)BATCH * NCHUNK * QDN;
  float* Hin  = p; p += (size_t)BATCH * NCHUNK * QDN;
  float* yfin = p; p += (size_t)TT * 192;
  float* yg   = p; p += (size_t)TT * 192;

  // 1. LayerNorm
  ln_kernel<<<TT / 4, 256, 0, stream>>>(x, norm_w, norm_b, xn);
  // 2. in_proj: xn(18432x96) @ W(96x384) -> xz0
  gemm_kernel<0><<<dim3(TT / 128, 6), 256, 0, stream>>>(xn, 96, in_proj_w, 384, xz0, 384, 384, 96, nullptr, 0);
  // 3. dw 3x3 conv + SiLU -> xc
  conv2d_silu_kernel<<<TT * 48 / 256, 256, 0, stream>>>(xz0, conv2d_w, xc);
  // 4. m_in_proj: xc @ W(192x384) -> xz1
  gemm_kernel<0><<<dim3(TT / 128, 6), 256, 0, stream>>>(xc, 192, m_in_proj, 384, xz1, 384, 384, 192, nullptr, 0);
  // 5. causal conv1d + bias + SiLU -> xmb
  conv1d_silu_kernel<<<TT * 48 / 256, 256, 0, stream>>>(xz1, m_c1d_w, m_c1d_b, xmb);
  // 6. x_proj: xmb @ W(192x44) -> xdbl
  gemm_kernel<0><<<dim3(TT / 128, 1), 256, 0, stream>>>(xmb, 192, m_x_proj, 44, xdbl, 44, 44, 192, nullptr, 0);
  // 7. dt_proj + softplus -> dlt
  dtproj_kernel<<<TT * 192 / 256, 256, 0, stream>>>(xdbl, m_dt_w, m_dt_b, dlt);
  // 8-10. chunked selective scan (+ u*D + silu(z) gate fused) -> yfin
  scan_phase1_kernel<<<BATCH * NCHUNK * QDN / 256, 256, 0, stream>>>(dlt, xmb, xdbl, m_A_log, Pb, Eb);
  scan_phase2_kernel<<<BATCH * QDN / 256, 256, 0, stream>>>(Pb, Eb, Hin);
  scan_phase3_kernel<<<BATCH * NCHUNK * QDN / 256, 256, 0, stream>>>(dlt, xmb, xdbl, m_A_log, m_D, xz1, Hin, yfin);
  // 11. m_out_proj with silu(x_gate) epilogue -> yg
  gemm_kernel<1><<<dim3(TT / 128, 3), 256, 0, stream>>>(yfin, 192, m_out_w, 192, yg, 192, 192, 192, xz0 + 192, 384);
  // 12. out_proj with residual epilogue -> out
  gemm_kernel<2><<<dim3(TT / 128, 2), 256, 0, stream>>>(yg, 192, out_w, 96, out, 96, 96, 192, x, 96);
}

// Round 2
// 357.082 us; speedup vs baseline: 1.2390x; 1.2390x over previous
//
#include <hip/hip_runtime.h>

#define DEV_INLINE __device__ __forceinline__

constexpr int BATCH = 2;
constexpr int HH = 96, WW = 96, CC = 96;
constexpr int DI = 192;            // d_inner == d_model for mamba
constexpr int NS = 16;             // d_state
constexpr int LSEQ = HH * WW;      // 9216
constexpr int TT = BATCH * LSEQ;   // 18432 tokens
constexpr int CHUNK = 48;          // scan chunk length
constexpr int NCHUNK = LSEQ / CHUNK; // 192 chunks per batch
constexpr int QDN = DI * NS;       // 3072

DEV_INLINE float silu_f(float x) { return x / (1.f + __expf(-x)); }
DEV_INLINE float softplus_f(float x) {
  return fmaxf(x, 0.f) + log1pf(__expf(-fabsf(x)));
}

// ---------------- LayerNorm over C=96, one wave per token ----------------
__global__ __launch_bounds__(256)
void ln_kernel(const float* __restrict__ x, const float* __restrict__ w,
               const float* __restrict__ bb, float* __restrict__ xn)
{
  int wid = (blockIdx.x * blockDim.x + threadIdx.x) >> 6;  // token
  int lane = threadIdx.x & 63;
  if (wid >= TT) return;
  const float* xr = x + (size_t)wid * CC;
  float v0 = xr[lane];
  float v1 = (lane < 32) ? xr[64 + lane] : 0.f;
  float s = v0 + v1, ss = v0 * v0 + v1 * v1;
#pragma unroll
  for (int off = 32; off >= 1; off >>= 1) {
    s  += __shfl_xor(s, off);
    ss += __shfl_xor(ss, off);
  }
  float mean = s * (1.f / 96.f);
  float var  = ss * (1.f / 96.f) - mean * mean;
  float rstd = rsqrtf(var + 1e-5f);
  float* o = xn + (size_t)wid * CC;
  o[lane] = (v0 - mean) * rstd * w[lane] + bb[lane];
  if (lane < 32) o[64 + lane] = (v1 - mean) * rstd * w[64 + lane] + bb[64 + lane];
}

// ---------------- generic fp32 GEMM: C[M,N] = A[M,K] @ B[K,N] ----------------
template<int EPI>
__global__ __launch_bounds__(256)
void gemm_kernel(const float* __restrict__ A, int lda,
                 const float* __restrict__ B, int ldb,
                 float* __restrict__ C, int ldc,
                 int N, int K,
                 const float* __restrict__ aux, int ldaux)
{
  __shared__ __align__(16) float As[16][132];
  __shared__ __align__(16) float Bs[16][64];
  const int tid = threadIdx.x;
  const int tx = tid & 15;
  const int ty = tid >> 4;
  const int m0 = blockIdx.x * 128;
  const int n0 = blockIdx.y * 64;
  const int arow = tid >> 2;
  const int akq  = (tid & 3) << 2;
  const int brow = tid >> 4;
  const int bcol = (tid & 15) << 2;

  float acc[8][4];
#pragma unroll
  for (int i = 0; i < 8; ++i)
#pragma unroll
    for (int j = 0; j < 4; ++j) acc[i][j] = 0.f;

  for (int k0 = 0; k0 < K; k0 += 16) {
    float4 a0 = *(const float4*)(A + (size_t)(m0 + arow) * lda + (k0 + akq));
    float4 a1 = *(const float4*)(A + (size_t)(m0 + arow + 64) * lda + (k0 + akq));
    float4 bv = make_float4(0.f, 0.f, 0.f, 0.f);
    if (n0 + bcol < N)
      bv = *(const float4*)(B + (size_t)(k0 + brow) * ldb + (n0 + bcol));
    __syncthreads();
    As[akq + 0][arow] = a0.x;
    As[akq + 1][arow] = a0.y;
    As[akq + 2][arow] = a0.z;
    As[akq + 3][arow] = a0.w;
    As[akq + 0][arow + 64] = a1.x;
    As[akq + 1][arow + 64] = a1.y;
    As[akq + 2][arow + 64] = a1.z;
    As[akq + 3][arow + 64] = a1.w;
    *(float4*)&Bs[brow][bcol] = bv;
    __syncthreads();
#pragma unroll
    for (int k = 0; k < 16; ++k) {
      float4 av0 = *(const float4*)&As[k][ty * 8];
      float4 av1 = *(const float4*)&As[k][ty * 8 + 4];
      float4 bv0 = *(const float4*)&Bs[k][tx * 4];
      float am[8] = {av0.x, av0.y, av0.z, av0.w, av1.x, av1.y, av1.z, av1.w};
      float bn[4] = {bv0.x, bv0.y, bv0.z, bv0.w};
#pragma unroll
      for (int i = 0; i < 8; ++i)
#pragma unroll
        for (int j = 0; j < 4; ++j)
          acc[i][j] = fmaf(am[i], bn[j], acc[i][j]);
    }
  }

  const int col = n0 + tx * 4;
  if (col < N) {
#pragma unroll
    for (int i = 0; i < 8; ++i) {
      const int row = m0 + ty * 8 + i;
      float4 v = make_float4(acc[i][0], acc[i][1], acc[i][2], acc[i][3]);
      if (EPI == 1) {
        const float4 g = *(const float4*)(aux + (size_t)row * ldaux + col);
        v.x *= silu_f(g.x); v.y *= silu_f(g.y); v.z *= silu_f(g.z); v.w *= silu_f(g.w);
      } else if (EPI == 2) {
        const float4 r = *(const float4*)(aux + (size_t)row * ldaux + col);
        v.x += r.x; v.y += r.y; v.z += r.z; v.w += r.w;
      }
      *(float4*)(C + (size_t)row * ldc + col) = v;
    }
  }
}

// ---------------- depthwise 3x3 conv + SiLU (channels-last) ----------------
__global__ __launch_bounds__(256)
void conv2d_silu_kernel(const float* __restrict__ xz0, const float* __restrict__ w,
                        float* __restrict__ xc)
{
  __shared__ float ws[DI * 9];
  for (int i = threadIdx.x; i < DI * 9; i += 256) ws[i] = w[i];
  __syncthreads();
  int id = blockIdx.x * 256 + threadIdx.x;     // TT*48
  int dq = id % 48;
  int p  = id / 48;
  int j = p % WW;
  int i = (p / WW) % HH;
  int b = p / (WW * HH);
  int d = dq * 4;
  float a0 = 0.f, a1 = 0.f, a2 = 0.f, a3 = 0.f;
#pragma unroll
  for (int ki = 0; ki < 3; ++ki) {
    int ii = i + ki - 1;
    if (ii < 0 || ii >= HH) continue;
#pragma unroll
    for (int kj = 0; kj < 3; ++kj) {
      int jj = j + kj - 1;
      if (jj < 0 || jj >= WW) continue;
      const float4 v = *(const float4*)(xz0 + ((size_t)((b * HH + ii) * WW + jj)) * 384 + d);
      int wk = ki * 3 + kj;
      a0 = fmaf(v.x, ws[(d + 0) * 9 + wk], a0);
      a1 = fmaf(v.y, ws[(d + 1) * 9 + wk], a1);
      a2 = fmaf(v.z, ws[(d + 2) * 9 + wk], a2);
      a3 = fmaf(v.w, ws[(d + 3) * 9 + wk], a3);
    }
  }
  float4 o = make_float4(silu_f(a0), silu_f(a1), silu_f(a2), silu_f(a3));
  *(float4*)(xc + (size_t)p * DI + d) = o;
}

// ---------------- causal depthwise conv1d (k=3) + bias + SiLU ----------------
__global__ __launch_bounds__(256)
void conv1d_silu_kernel(const float* __restrict__ xz1, const float* __restrict__ w,
                        const float* __restrict__ bias, float* __restrict__ xm)
{
  int id = blockIdx.x * 256 + threadIdx.x;   // TT*48
  int dq = id % 48;
  int t  = id / 48;
  int l  = t % LSEQ;
  int d  = dq * 4;
  float a0 = bias[d + 0], a1 = bias[d + 1], a2 = bias[d + 2], a3 = bias[d + 3];
#pragma unroll
  for (int k = 0; k < 3; ++k) {
    int ll = l + k - 2;
    if (ll < 0) continue;
    const float4 v = *(const float4*)(xz1 + (size_t)(t + k - 2) * 384 + d);
    a0 = fmaf(v.x, w[(d + 0) * 3 + k], a0);
    a1 = fmaf(v.y, w[(d + 1) * 3 + k], a1);
    a2 = fmaf(v.z, w[(d + 2) * 3 + k], a2);
    a3 = fmaf(v.w, w[(d + 3) * 3 + k], a3);
  }
  float4 o = make_float4(silu_f(a0), silu_f(a1), silu_f(a2), silu_f(a3));
  *(float4*)(xm + (size_t)t * DI + d) = o;
}

// ---------------- dt projection (K=12) + softplus -> delta (TT,192) ----------------
__global__ __launch_bounds__(256)
void dtproj_kernel(const float* __restrict__ xdbl, const float* __restrict__ Wdt,
                   const float* __restrict__ bdt, float* __restrict__ delta)
{
  int id = blockIdx.x * 256 + threadIdx.x;  // TT*192
  int d = id % DI;
  int t = id / DI;
  float acc = bdt[d];
#pragma unroll
  for (int r = 0; r < 12; ++r)
    acc = fmaf(xdbl[(size_t)t * 44 + r], Wdt[r * DI + d], acc);
  delta[id] = softplus_f(acc);
}

// ---------------- selective scan, 3-phase chunked (LDS-staged) ----------------
// Block: 256 threads covering 16 d x 16 n for one (b, chunk, d-block).
// Grid: BATCH * NCHUNK * 12.
__global__ __launch_bounds__(256)
void scan_phase1_kernel(const float* __restrict__ delta, const float* __restrict__ xm,
                        const float* __restrict__ xdbl, const float* __restrict__ Alog,
                        float* __restrict__ P, float* __restrict__ E)
{
  __shared__ float sD[CHUNK][16], sU[CHUNK][16], sB[CHUNK][16];
  const int bid = blockIdx.x;
  const int dblk = bid % 12;
  const int g = (bid / 12) % NCHUNK;
  const int b = bid / (12 * NCHUNK);
  const int tid = threadIdx.x;
  const int n = tid & 15, dj = tid >> 4;
  const int d = dblk * 16 + dj;
  const int t0 = b * LSEQ + g * CHUNK;
  if (tid < CHUNK * 4) {
    int t = tid >> 2, jq = (tid & 3) * 4;
    *(float4*)&sD[t][jq] = *(const float4*)(delta + (size_t)(t0 + t) * DI + dblk * 16 + jq);
    *(float4*)&sU[t][jq] = *(const float4*)(xm    + (size_t)(t0 + t) * DI + dblk * 16 + jq);
    *(float4*)&sB[t][jq] = *(const float4*)(xdbl  + (size_t)(t0 + t) * 44 + 12 + jq);
  }
  __syncthreads();
  const float Av = -__expf(Alog[d * NS + n]);
  float p = 1.f, e = 0.f;
#pragma unroll 4
  for (int l = 0; l < CHUNK; ++l) {
    float dl = sD[l][dj], u = sU[l][dj], Bv = sB[l][n];
    float a = __expf(dl * Av);
    p *= a;
    e = fmaf(a, e, dl * u * Bv);
  }
  size_t id = (size_t)bid * 256 + tid;
  P[id] = p;
  E[id] = e;
}

__global__ __launch_bounds__(256)
void scan_phase2_kernel(const float* __restrict__ P, const float* __restrict__ E,
                        float* __restrict__ Hin)
{
  int id = blockIdx.x * 256 + threadIdx.x;   // BATCH*QDN = 6144
  int q = id % QDN;
  int b = id / QDN;
  float carry = 0.f;
#pragma unroll 8
  for (int g = 0; g < NCHUNK; ++g) {
    size_t idx = (size_t)(b * NCHUNK + g) * QDN + q;
    Hin[idx] = carry;
    carry = fmaf(P[idx], carry, E[idx]);
  }
}

__global__ __launch_bounds__(256)
void scan_phase3_kernel(const float* __restrict__ delta, const float* __restrict__ xm,
                        const float* __restrict__ xdbl, const float* __restrict__ Alog,
                        const float* __restrict__ Dv, const float* __restrict__ xz1,
                        const float* __restrict__ Hin, float* __restrict__ yout)
{
  __shared__ float sD[CHUNK][16], sU[CHUNK][16], sB[CHUNK][16], sC[CHUNK][16], sY[CHUNK][16];
  const int bid = blockIdx.x;
  const int dblk = bid % 12;
  const int g = (bid / 12) % NCHUNK;
  const int b = bid / (12 * NCHUNK);
  const int tid = threadIdx.x;
  const int n = tid & 15, dj = tid >> 4;
  const int d = dblk * 16 + dj;
  const int t0 = b * LSEQ + g * CHUNK;
  if (tid < CHUNK * 4) {
    int t = tid >> 2, jq = (tid & 3) * 4;
    *(float4*)&sD[t][jq] = *(const float4*)(delta + (size_t)(t0 + t) * DI + dblk * 16 + jq);
    *(float4*)&sU[t][jq] = *(const float4*)(xm    + (size_t)(t0 + t) * DI + dblk * 16 + jq);
    *(float4*)&sB[t][jq] = *(const float4*)(xdbl  + (size_t)(t0 + t) * 44 + 12 + jq);
    *(float4*)&sC[t][jq] = *(const float4*)(xdbl  + (size_t)(t0 + t) * 44 + 28 + jq);
  }
  __syncthreads();
  const float Av = -__expf(Alog[d * NS + n]);
  const float Dd = Dv[d];
  float h = Hin[(size_t)bid * 256 + tid];
#pragma unroll 4
  for (int l = 0; l < CHUNK; ++l) {
    float dl = sD[l][dj], u = sU[l][dj], Bv = sB[l][n], Cv = sC[l][n];
    float a = __expf(dl * Av);
    h = fmaf(a, h, dl * u * Bv);
    float yp = h * Cv;
    yp += __shfl_xor(yp, 8, 16);
    yp += __shfl_xor(yp, 4, 16);
    yp += __shfl_xor(yp, 2, 16);
    yp += __shfl_xor(yp, 1, 16);
    if (n == 0) sY[l][dj] = fmaf(u, Dd, yp);
  }
  __syncthreads();
  if (tid < CHUNK * 4) {
    int t = tid >> 2, jq = (tid & 3) * 4;
    float4 y4 = *(float4*)&sY[t][jq];
    const float4 z4 = *(const float4*)(xz1 + (size_t)(t0 + t) * 384 + 192 + dblk * 16 + jq);
    y4.x *= silu_f(z4.x);
    y4.y *= silu_f(z4.y);
    y4.z *= silu_f(z4.z);
    y4.w *= silu_f(z4.w);
    *(float4*)(yout + (size_t)(t0 + t) * DI + dblk * 16 + jq) = y4;
  }
}

// ---------------- launch ----------------
extern "C" void kernel_launch(void* const* d_in, const int* in_sizes, int n_in,
                              void* d_out, int out_size, void* d_ws, size_t ws_size,
                              hipStream_t stream)
{
  const float* x         = (const float*)d_in[0];
  const float* norm_w    = (const float*)d_in[1];
  const float* norm_b    = (const float*)d_in[2];
  const float* in_proj_w = (const float*)d_in[3];
  const float* conv2d_w  = (const float*)d_in[4];
  const float* m_in_proj = (const float*)d_in[5];
  const float* m_c1d_w   = (const float*)d_in[6];
  const float* m_c1d_b   = (const float*)d_in[7];
  const float* m_x_proj  = (const float*)d_in[8];
  const float* m_dt_w    = (const float*)d_in[9];
  const float* m_dt_b    = (const float*)d_in[10];
  const float* m_A_log   = (const float*)d_in[11];
  const float* m_D       = (const float*)d_in[12];
  const float* m_out_w   = (const float*)d_in[13];
  const float* out_w     = (const float*)d_in[14];
  float* out = (float*)d_out;

  float* p = (float*)d_ws;
  float* xn   = p; p += (size_t)TT * 96;    // also reused as P after step 2
  float* xz0  = p; p += (size_t)TT * 384;   // x_in | x_gate
  float* xc   = p; p += (size_t)TT * 192;   // also reused as E after step 4
  float* xz1  = p; p += (size_t)TT * 384;   // xm_pre | z
  float* xmb  = p; p += (size_t)TT * 192;
  float* xdbl = p; p += (size_t)TT * 44;    // dt | B | C
  float* dlt  = p; p += (size_t)TT * 192;
  float* Hin  = p; p += (size_t)BATCH * NCHUNK * QDN;
  float* yfin = p; p += (size_t)TT * 192;
  float* yg   = p; p += (size_t)TT * 192;
  // P/E alias buffers that are dead by the time the scan runs:
  float* Pb = xn;   // needs BATCH*NCHUNK*QDN = 1.18M floats <= TT*96 = 1.77M
  float* Eb = xc;   // needs 1.18M <= TT*192 = 3.54M  (xc consumed by gemm #4)

  // 1. LayerNorm
  ln_kernel<<<TT / 4, 256, 0, stream>>>(x, norm_w, norm_b, xn);
  // 2. in_proj: xn(18432x96) @ W(96x384) -> xz0
  gemm_kernel<0><<<dim3(TT / 128, 6), 256, 0, stream>>>(xn, 96, in_proj_w, 384, xz0, 384, 384, 96, nullptr, 0);
  // 3. dw 3x3 conv + SiLU -> xc
  conv2d_silu_kernel<<<TT * 48 / 256, 256, 0, stream>>>(xz0, conv2d_w, xc);
  // 4. m_in_proj: xc @ W(192x384) -> xz1
  gemm_kernel<0><<<dim3(TT / 128, 6), 256, 0, stream>>>(xc, 192, m_in_proj, 384, xz1, 384, 384, 192, nullptr, 0);
  // 5. causal conv1d + bias + SiLU -> xmb
  conv1d_silu_kernel<<<TT * 48 / 256, 256, 0, stream>>>(xz1, m_c1d_w, m_c1d_b, xmb);
  // 6. x_proj: xmb @ W(192x44) -> xdbl
  gemm_kernel<0><<<dim3(TT / 128, 1), 256, 0, stream>>>(xmb, 192, m_x_proj, 44, xdbl, 44, 44, 192, nullptr, 0);
  // 7. dt_proj + softplus -> dlt
  dtproj_kernel<<<TT * 192 / 256, 256, 0, stream>>>(xdbl, m_dt_w, m_dt_b, dlt);
  // 8-10. chunked selective scan (+ u*D + silu(z) gate fused) -> yfin
  scan_phase1_kernel<<<BATCH * NCHUNK * 12, 256, 0, stream>>>(dlt, xmb, xdbl, m_A_log, Pb, Eb);
  scan_phase2_kernel<<<BATCH * QDN / 256, 256, 0, stream>>>(Pb, Eb, Hin);
  scan_phase3_kernel<<<BATCH * NCHUNK * 12, 256, 0, stream>>>(dlt, xmb, xdbl, m_A_log, m_D, xz1, Hin, yfin);
  // 11. m_out_proj with silu(x_gate) epilogue -> yg
  gemm_kernel<1><<<dim3(TT / 128, 3), 256, 0, stream>>>(yfin, 192, m_out_w, 192, yg, 192, 192, 192, xz0 + 192, 384);
  // 12. out_proj with residual epilogue -> out
  gemm_kernel<2><<<dim3(TT / 128, 2), 256, 0, stream>>>(yg, 192, out_w, 96, out, 96, 96, 192, x, 96);
}

// Round 3
// 271.002 us; speedup vs baseline: 1.6326x; 1.3176x over previous
//
#include <hip/hip_runtime.h>

#define DEV_INLINE __device__ __forceinline__

constexpr int BATCH = 2;
constexpr int HH = 96, WW = 96, CC = 96;
constexpr int DI = 192;              // d_inner == mamba d_model
constexpr int NS = 16;               // d_state
constexpr int LSEQ = HH * WW;        // 9216
constexpr int TT = BATCH * LSEQ;     // 18432 tokens
constexpr int CHUNK = 32;            // scan chunk length
constexpr int NCHUNK = LSEQ / CHUNK; // 288 chunks per batch
constexpr int SUP = 24;              // chunks per super-chunk
constexpr int NSUP = NCHUNK / SUP;   // 12
constexpr int QDN = DI * NS;         // 3072

typedef __attribute__((ext_vector_type(8))) short bf16x8;
typedef __attribute__((ext_vector_type(4))) float f32x4;

DEV_INLINE float silu_f(float x) { return x / (1.f + __expf(-x)); }
DEV_INLINE float softplus_f(float x) {
  return fmaxf(x, 0.f) + log1pf(__expf(-fabsf(x)));
}
DEV_INLINE ushort f2bf(float f) {
  union { float f; unsigned u; } c; c.f = f;
  unsigned u = c.u + 0x7FFF + ((c.u >> 16) & 1);   // RNE
  return (ushort)(u >> 16);
}

// ---------------- weight cast + transpose to bf16 [N][K] ----------------
// seg0: in_proj  W[96 x384] -> Wt0[384][96]
// seg1: m_in     W[192x384] -> Wt1[384][192]
// seg2: m_out    W[192x192] -> Wt2[192][192]
// seg3: out_proj W[192x 96] -> Wt3[128][192] (rows 96..127 zero pad)
__global__ __launch_bounds__(256)
void castw_kernel(const float* __restrict__ w0, const float* __restrict__ w1,
                  const float* __restrict__ w2, const float* __restrict__ w3,
                  ushort* __restrict__ t0, ushort* __restrict__ t1,
                  ushort* __restrict__ t2, ushort* __restrict__ t3)
{
  int id = blockIdx.x * 256 + threadIdx.x;      // 172032 total
  if (id < 36864) {
    int k = id % 96, n = id / 96;
    t0[id] = f2bf(w0[k * 384 + n]);
  } else if (id < 110592) {
    int j = id - 36864; int k = j % 192, n = j / 192;
    t1[j] = f2bf(w1[k * 384 + n]);
  } else if (id < 147456) {
    int j = id - 110592; int k = j % 192, n = j / 192;
    t2[j] = f2bf(w2[k * 192 + n]);
  } else {
    int j = id - 147456; int k = j % 192, n = j / 192;
    t3[j] = (n < 96) ? f2bf(w3[k * 96 + n]) : (ushort)0;
  }
}

// ---------------- LayerNorm over C=96 -> bf16, one wave per token ----------------
__global__ __launch_bounds__(256)
void ln_kernel(const float* __restrict__ x, const float* __restrict__ w,
               const float* __restrict__ bb, ushort* __restrict__ xn)
{
  int wid = (blockIdx.x * blockDim.x + threadIdx.x) >> 6;  // token
  int lane = threadIdx.x & 63;
  if (wid >= TT) return;
  const float* xr = x + (size_t)wid * CC;
  float v0 = xr[lane];
  float v1 = (lane < 32) ? xr[64 + lane] : 0.f;
  float s = v0 + v1, ss = v0 * v0 + v1 * v1;
#pragma unroll
  for (int off = 32; off >= 1; off >>= 1) {
    s  += __shfl_xor(s, off);
    ss += __shfl_xor(ss, off);
  }
  float mean = s * (1.f / 96.f);
  float var  = ss * (1.f / 96.f) - mean * mean;
  float rstd = rsqrtf(var + 1e-5f);
  ushort* o = xn + (size_t)wid * CC;
  o[lane] = f2bf((v0 - mean) * rstd * w[lane] + bb[lane]);
  if (lane < 32) o[64 + lane] = f2bf((v1 - mean) * rstd * w[64 + lane] + bb[64 + lane]);
}

// ---------------- bf16 MFMA GEMM: C[M,N] = A[M,K] @ W[K,N] ----------------
// A row-major bf16 [M x K]; Bt = W^T bf16 [Npad x K].
// Block 256 = 4 waves (2x2); block tile 128x64; wave tile 64x32 (4x2 mfma 16x16x32).
// EPI: 0 none, 1 mul silu(aux), 2 add aux.  OUTF: 0 fp32, 1 bf16.
template<int EPI, int OUTF>
__global__ __launch_bounds__(256)
void mfma_gemm_kernel(const ushort* __restrict__ A, int lda,
                      const ushort* __restrict__ Bt, int ldb,
                      void* __restrict__ Cout, int ldc, int N, int K,
                      const float* __restrict__ aux, int ldaux)
{
  const int tid = threadIdx.x;
  const int wid = tid >> 6, lane = tid & 63;
  const int wm = wid >> 1, wn = wid & 1;
  const int m0 = blockIdx.x * 128 + wm * 64;
  const int n0 = blockIdx.y * 64 + wn * 32;
  const int row16 = lane & 15, quad = lane >> 4;

  f32x4 acc[4][2];
  const f32x4 z4 = {0.f, 0.f, 0.f, 0.f};
#pragma unroll
  for (int i = 0; i < 4; ++i)
#pragma unroll
    for (int j = 0; j < 2; ++j) acc[i][j] = z4;

  for (int k0 = 0; k0 < K; k0 += 32) {
    bf16x8 a[4], b[2];
#pragma unroll
    for (int i = 0; i < 4; ++i)
      a[i] = *(const bf16x8*)(A + (size_t)(m0 + i * 16 + row16) * lda + k0 + quad * 8);
#pragma unroll
    for (int j = 0; j < 2; ++j)
      b[j] = *(const bf16x8*)(Bt + (size_t)(n0 + j * 16 + row16) * ldb + k0 + quad * 8);
#pragma unroll
    for (int i = 0; i < 4; ++i)
#pragma unroll
      for (int j = 0; j < 2; ++j)
        acc[i][j] = __builtin_amdgcn_mfma_f32_16x16x32_bf16(a[i], b[j], acc[i][j], 0, 0, 0);
  }

#pragma unroll
  for (int i = 0; i < 4; ++i) {
    const int rowb = m0 + i * 16 + quad * 4;
#pragma unroll
    for (int j = 0; j < 2; ++j) {
      const int col = n0 + j * 16 + row16;
      if (col < N) {
#pragma unroll
        for (int r = 0; r < 4; ++r) {
          float v = acc[i][j][r];
          const int row = rowb + r;
          if (EPI == 1) v *= silu_f(aux[(size_t)row * ldaux + col]);
          else if (EPI == 2) v += aux[(size_t)row * ldaux + col];
          if (OUTF == 0) ((float*)Cout)[(size_t)row * ldc + col] = v;
          else ((ushort*)Cout)[(size_t)row * ldc + col] = f2bf(v);
        }
      }
    }
  }
}

// ---------------- fp32 vector GEMM (kept for x_proj, N=44) ----------------
__global__ __launch_bounds__(256)
void gemm_f32_kernel(const float* __restrict__ A, int lda,
                     const float* __restrict__ B, int ldb,
                     float* __restrict__ C, int ldc, int N, int K)
{
  __shared__ __align__(16) float As[16][132];
  __shared__ __align__(16) float Bs[16][64];
  const int tid = threadIdx.x;
  const int tx = tid & 15;
  const int ty = tid >> 4;
  const int m0 = blockIdx.x * 128;
  const int n0 = blockIdx.y * 64;
  const int arow = tid >> 2;
  const int akq  = (tid & 3) << 2;
  const int brow = tid >> 4;
  const int bcol = (tid & 15) << 2;

  float acc[8][4];
#pragma unroll
  for (int i = 0; i < 8; ++i)
#pragma unroll
    for (int j = 0; j < 4; ++j) acc[i][j] = 0.f;

  for (int k0 = 0; k0 < K; k0 += 16) {
    float4 a0 = *(const float4*)(A + (size_t)(m0 + arow) * lda + (k0 + akq));
    float4 a1 = *(const float4*)(A + (size_t)(m0 + arow + 64) * lda + (k0 + akq));
    float4 bv = make_float4(0.f, 0.f, 0.f, 0.f);
    if (n0 + bcol < N)
      bv = *(const float4*)(B + (size_t)(k0 + brow) * ldb + (n0 + bcol));
    __syncthreads();
    As[akq + 0][arow] = a0.x;
    As[akq + 1][arow] = a0.y;
    As[akq + 2][arow] = a0.z;
    As[akq + 3][arow] = a0.w;
    As[akq + 0][arow + 64] = a1.x;
    As[akq + 1][arow + 64] = a1.y;
    As[akq + 2][arow + 64] = a1.z;
    As[akq + 3][arow + 64] = a1.w;
    *(float4*)&Bs[brow][bcol] = bv;
    __syncthreads();
#pragma unroll
    for (int k = 0; k < 16; ++k) {
      float4 av0 = *(const float4*)&As[k][ty * 8];
      float4 av1 = *(const float4*)&As[k][ty * 8 + 4];
      float4 bv0 = *(const float4*)&Bs[k][tx * 4];
      float am[8] = {av0.x, av0.y, av0.z, av0.w, av1.x, av1.y, av1.z, av1.w};
      float bn[4] = {bv0.x, bv0.y, bv0.z, bv0.w};
#pragma unroll
      for (int i = 0; i < 8; ++i)
#pragma unroll
        for (int j = 0; j < 4; ++j)
          acc[i][j] = fmaf(am[i], bn[j], acc[i][j]);
    }
  }

  const int col = n0 + tx * 4;
  if (col < N) {
#pragma unroll
    for (int i = 0; i < 8; ++i) {
      const int row = m0 + ty * 8 + i;
      *(float4*)(C + (size_t)row * ldc + col) =
          make_float4(acc[i][0], acc[i][1], acc[i][2], acc[i][3]);
    }
  }
}

// ---------------- depthwise 3x3 conv + SiLU -> bf16 (channels-last) ----------------
__global__ __launch_bounds__(256)
void conv2d_silu_kernel(const float* __restrict__ xz0, const float* __restrict__ w,
                        ushort* __restrict__ xc)
{
  __shared__ float ws[DI * 9];
  for (int i = threadIdx.x; i < DI * 9; i += 256) ws[i] = w[i];
  __syncthreads();
  int id = blockIdx.x * 256 + threadIdx.x;     // TT*48
  int dq = id % 48;
  int p  = id / 48;
  int j = p % WW;
  int i = (p / WW) % HH;
  int b = p / (WW * HH);
  int d = dq * 4;
  float a0 = 0.f, a1 = 0.f, a2 = 0.f, a3 = 0.f;
#pragma unroll
  for (int ki = 0; ki < 3; ++ki) {
    int ii = i + ki - 1;
    if (ii < 0 || ii >= HH) continue;
#pragma unroll
    for (int kj = 0; kj < 3; ++kj) {
      int jj = j + kj - 1;
      if (jj < 0 || jj >= WW) continue;
      const float4 v = *(const float4*)(xz0 + ((size_t)((b * HH + ii) * WW + jj)) * 384 + d);
      int wk = ki * 3 + kj;
      a0 = fmaf(v.x, ws[(d + 0) * 9 + wk], a0);
      a1 = fmaf(v.y, ws[(d + 1) * 9 + wk], a1);
      a2 = fmaf(v.z, ws[(d + 2) * 9 + wk], a2);
      a3 = fmaf(v.w, ws[(d + 3) * 9 + wk], a3);
    }
  }
  ushort4 o;
  o.x = f2bf(silu_f(a0)); o.y = f2bf(silu_f(a1));
  o.z = f2bf(silu_f(a2)); o.w = f2bf(silu_f(a3));
  *(ushort4*)(xc + (size_t)p * DI + d) = o;
}

// ---------------- causal depthwise conv1d (k=3) + bias + SiLU ----------------
__global__ __launch_bounds__(256)
void conv1d_silu_kernel(const float* __restrict__ xz1, const float* __restrict__ w,
                        const float* __restrict__ bias, float* __restrict__ xm)
{
  int id = blockIdx.x * 256 + threadIdx.x;   // TT*48
  int dq = id % 48;
  int t  = id / 48;
  int l  = t % LSEQ;
  int d  = dq * 4;
  float a0 = bias[d + 0], a1 = bias[d + 1], a2 = bias[d + 2], a3 = bias[d + 3];
#pragma unroll
  for (int k = 0; k < 3; ++k) {
    int ll = l + k - 2;
    if (ll < 0) continue;
    const float4 v = *(const float4*)(xz1 + (size_t)(t + k - 2) * 384 + d);
    a0 = fmaf(v.x, w[(d + 0) * 3 + k], a0);
    a1 = fmaf(v.y, w[(d + 1) * 3 + k], a1);
    a2 = fmaf(v.z, w[(d + 2) * 3 + k], a2);
    a3 = fmaf(v.w, w[(d + 3) * 3 + k], a3);
  }
  float4 o = make_float4(silu_f(a0), silu_f(a1), silu_f(a2), silu_f(a3));
  *(float4*)(xm + (size_t)t * DI + d) = o;
}

// ---------------- dt projection (K=12) + softplus -> delta (TT,192) ----------------
__global__ __launch_bounds__(256)
void dtproj_kernel(const float* __restrict__ xdbl, const float* __restrict__ Wdt,
                   const float* __restrict__ bdt, float* __restrict__ delta)
{
  int id = blockIdx.x * 256 + threadIdx.x;  // TT*192
  int d = id % DI;
  int t = id / DI;
  float acc = bdt[d];
#pragma unroll
  for (int r = 0; r < 12; ++r)
    acc = fmaf(xdbl[(size_t)t * 44 + r], Wdt[r * DI + d], acc);
  delta[id] = softplus_f(acc);
}

// ---------------- selective scan: thread = (b, chunk, d), 16 n-states in regs ----------------
__global__ __launch_bounds__(192)
void scan1_kernel(const float* __restrict__ dlt, const float* __restrict__ xmb,
                  const float* __restrict__ xdbl, const float* __restrict__ Alog,
                  float* __restrict__ P, float* __restrict__ E)
{
  const int d = threadIdx.x;               // 0..191
  const int g = blockIdx.x % NCHUNK;
  const int b = blockIdx.x / NCHUNK;
  const int t0 = b * LSEQ + g * CHUNK;
  float Av[16];
#pragma unroll
  for (int j = 0; j < 16; ++j) Av[j] = -__expf(Alog[d * 16 + j]);
  float e[16];
#pragma unroll
  for (int j = 0; j < 16; ++j) e[j] = 0.f;
  float sdl = 0.f;
#pragma unroll 2
  for (int l = 0; l < CHUNK; ++l) {
    const int t = t0 + l;
    float dl = dlt[(size_t)t * DI + d];
    float u  = xmb[(size_t)t * DI + d];
    const float4 B0 = *(const float4*)(xdbl + (size_t)t * 44 + 12);
    const float4 B1 = *(const float4*)(xdbl + (size_t)t * 44 + 16);
    const float4 B2 = *(const float4*)(xdbl + (size_t)t * 44 + 20);
    const float4 B3 = *(const float4*)(xdbl + (size_t)t * 44 + 24);
    const float Bv[16] = {B0.x, B0.y, B0.z, B0.w, B1.x, B1.y, B1.z, B1.w,
                          B2.x, B2.y, B2.z, B2.w, B3.x, B3.y, B3.z, B3.w};
    float du = dl * u;
    sdl += dl;
#pragma unroll
    for (int j = 0; j < 16; ++j) {
      float a = __expf(dl * Av[j]);
      e[j] = fmaf(a, e[j], du * Bv[j]);
    }
  }
  size_t base = ((size_t)(b * NCHUNK + g)) * QDN + d * 16;
#pragma unroll
  for (int j = 0; j < 16; ++j) {
    P[base + j] = __expf(Av[j] * sdl);
    E[base + j] = e[j];
  }
}

// level-2a: per super-chunk product/accum over SUP chunks
__global__ __launch_bounds__(256)
void scan2a_kernel(const float* __restrict__ P, const float* __restrict__ E,
                   float* __restrict__ SP, float* __restrict__ SE)
{
  int id = blockIdx.x * 256 + threadIdx.x;  // BATCH*NSUP*QDN = 73728
  int q = id % QDN;
  int s = (id / QDN) % NSUP;
  int b = id / (QDN * NSUP);
  float cp = 1.f, ce = 0.f;
#pragma unroll 4
  for (int c = 0; c < SUP; ++c) {
    size_t idx = ((size_t)(b * NCHUNK + s * SUP + c)) * QDN + q;
    float p = P[idx], e = E[idx];
    ce = fmaf(p, ce, e);
    cp *= p;
  }
  SP[id] = cp; SE[id] = ce;
}

// level-2b: serial scan over NSUP super-chunks
__global__ __launch_bounds__(256)
void scan2b_kernel(const float* __restrict__ SP, const float* __restrict__ SE,
                   float* __restrict__ Hsup)
{
  int id = blockIdx.x * 256 + threadIdx.x;  // BATCH*QDN = 6144
  int q = id % QDN;
  int b = id / QDN;
  float carry = 0.f;
#pragma unroll
  for (int s = 0; s < NSUP; ++s) {
    size_t idx = ((size_t)(b * NSUP + s)) * QDN + q;
    Hsup[idx] = carry;
    carry = fmaf(SP[idx], carry, SE[idx]);
  }
}

// level-2c: expand to per-chunk inbound states
__global__ __launch_bounds__(256)
void scan2c_kernel(const float* __restrict__ P, const float* __restrict__ E,
                   const float* __restrict__ Hsup, float* __restrict__ Hin)
{
  int id = blockIdx.x * 256 + threadIdx.x;  // 73728
  int q = id % QDN;
  int s = (id / QDN) % NSUP;
  int b = id / (QDN * NSUP);
  float h = Hsup[id];
#pragma unroll 4
  for (int c = 0; c < SUP; ++c) {
    size_t idx = ((size_t)(b * NCHUNK + s * SUP + c)) * QDN + q;
    Hin[idx] = h;
    h = fmaf(P[idx], h, E[idx]);
  }
}

// phase3: replay chunk, y = (sum_n h*C + u*D) * silu(z) -> bf16
__global__ __launch_bounds__(192)
void scan3_kernel(const float* __restrict__ dlt, const float* __restrict__ xmb,
                  const float* __restrict__ xdbl, const float* __restrict__ Alog,
                  const float* __restrict__ Dv, const float* __restrict__ xz1,
                  const float* __restrict__ Hin, ushort* __restrict__ yout)
{
  const int d = threadIdx.x;
  const int g = blockIdx.x % NCHUNK;
  const int b = blockIdx.x / NCHUNK;
  const int t0 = b * LSEQ + g * CHUNK;
  float Av[16];
#pragma unroll
  for (int j = 0; j < 16; ++j) Av[j] = -__expf(Alog[d * 16 + j]);
  const float Dd = Dv[d];
  float h[16];
  {
    size_t hb = ((size_t)(b * NCHUNK + g)) * QDN + d * 16;
#pragma unroll
    for (int j = 0; j < 16; ++j) h[j] = Hin[hb + j];
  }
#pragma unroll 2
  for (int l = 0; l < CHUNK; ++l) {
    const int t = t0 + l;
    float dl = dlt[(size_t)t * DI + d];
    float u  = xmb[(size_t)t * DI + d];
    const float4 B0 = *(const float4*)(xdbl + (size_t)t * 44 + 12);
    const float4 B1 = *(const float4*)(xdbl + (size_t)t * 44 + 16);
    const float4 B2 = *(const float4*)(xdbl + (size_t)t * 44 + 20);
    const float4 B3 = *(const float4*)(xdbl + (size_t)t * 44 + 24);
    const float4 C0 = *(const float4*)(xdbl + (size_t)t * 44 + 28);
    const float4 C1 = *(const float4*)(xdbl + (size_t)t * 44 + 32);
    const float4 C2 = *(const float4*)(xdbl + (size_t)t * 44 + 36);
    const float4 C3 = *(const float4*)(xdbl + (size_t)t * 44 + 40);
    const float Bv[16] = {B0.x, B0.y, B0.z, B0.w, B1.x, B1.y, B1.z, B1.w,
                          B2.x, B2.y, B2.z, B2.w, B3.x, B3.y, B3.z, B3.w};
    const float Cv[16] = {C0.x, C0.y, C0.z, C0.w, C1.x, C1.y, C1.z, C1.w,
                          C2.x, C2.y, C2.z, C2.w, C3.x, C3.y, C3.z, C3.w};
    float du = dl * u;
    float y0 = 0.f, y1 = 0.f, y2 = 0.f, y3 = 0.f;
#pragma unroll
    for (int j = 0; j < 16; ++j) {
      float a = __expf(dl * Av[j]);
      h[j] = fmaf(a, h[j], du * Bv[j]);
      if ((j & 3) == 0) y0 = fmaf(h[j], Cv[j], y0);
      else if ((j & 3) == 1) y1 = fmaf(h[j], Cv[j], y1);
      else if ((j & 3) == 2) y2 = fmaf(h[j], Cv[j], y2);
      else y3 = fmaf(h[j], Cv[j], y3);
    }
    float y = (y0 + y1) + (y2 + y3) + u * Dd;
    float z = xz1[(size_t)t * 384 + 192 + d];
    yout[(size_t)t * DI + d] = f2bf(y * silu_f(z));
  }
}

// ---------------- launch ----------------
extern "C" void kernel_launch(void* const* d_in, const int* in_sizes, int n_in,
                              void* d_out, int out_size, void* d_ws, size_t ws_size,
                              hipStream_t stream)
{
  const float* x         = (const float*)d_in[0];
  const float* norm_w    = (const float*)d_in[1];
  const float* norm_b    = (const float*)d_in[2];
  const float* in_proj_w = (const float*)d_in[3];
  const float* conv2d_w  = (const float*)d_in[4];
  const float* m_in_proj = (const float*)d_in[5];
  const float* m_c1d_w   = (const float*)d_in[6];
  const float* m_c1d_b   = (const float*)d_in[7];
  const float* m_x_proj  = (const float*)d_in[8];
  const float* m_dt_w    = (const float*)d_in[9];
  const float* m_dt_b    = (const float*)d_in[10];
  const float* m_A_log   = (const float*)d_in[11];
  const float* m_D       = (const float*)d_in[12];
  const float* m_out_w   = (const float*)d_in[13];
  const float* out_w     = (const float*)d_in[14];
  float* out = (float*)d_out;

  char* wp = (char*)d_ws;
  auto alloc = [&](size_t bytes) {
    char* r = wp; wp += (bytes + 255) & ~(size_t)255; return r;
  };
  ushort* Wt0   = (ushort*)alloc(36864 * 2);        // [384][96]
  ushort* Wt1   = (ushort*)alloc(73728 * 2);        // [384][192]
  ushort* Wt2   = (ushort*)alloc(36864 * 2);        // [192][192]
  ushort* Wt3   = (ushort*)alloc(24576 * 2);        // [128][192]
  ushort* xn_bf = (ushort*)alloc((size_t)TT * 96 * 2);
  float*  xz0   = (float*)alloc((size_t)TT * 384 * 4);   // x_in | x_gate
  ushort* xc_bf = (ushort*)alloc((size_t)TT * 192 * 2);
  float*  xz1   = (float*)alloc((size_t)TT * 384 * 4);   // xm_pre | z
  float*  xmb   = (float*)alloc((size_t)TT * 192 * 4);
  float*  xdbl  = (float*)alloc((size_t)TT * 44 * 4);    // dt | B | C
  float*  dlt   = (float*)alloc((size_t)TT * 192 * 4);
  float*  Pb    = (float*)alloc((size_t)BATCH * NCHUNK * QDN * 4);
  float*  Eb    = (float*)alloc((size_t)BATCH * NCHUNK * QDN * 4);
  float*  Hin   = (float*)alloc((size_t)BATCH * NCHUNK * QDN * 4);
  float*  SPb   = (float*)alloc((size_t)BATCH * NSUP * QDN * 4);
  float*  SEb   = (float*)alloc((size_t)BATCH * NSUP * QDN * 4);
  float*  Hsup  = (float*)alloc((size_t)BATCH * NSUP * QDN * 4);
  ushort* yfin  = (ushort*)alloc((size_t)TT * 192 * 2);
  ushort* yg    = (ushort*)alloc((size_t)TT * 192 * 2);

  // 0. weight cast+transpose
  castw_kernel<<<672, 256, 0, stream>>>(in_proj_w, m_in_proj, m_out_w, out_w,
                                        Wt0, Wt1, Wt2, Wt3);
  // 1. LayerNorm -> bf16
  ln_kernel<<<TT / 4, 256, 0, stream>>>(x, norm_w, norm_b, xn_bf);
  // 2. in_proj (MFMA): xn_bf @ W0 -> xz0 fp32 (18432x384)
  mfma_gemm_kernel<0, 0><<<dim3(TT / 128, 6), 256, 0, stream>>>(
      xn_bf, 96, Wt0, 96, xz0, 384, 384, 96, nullptr, 0);
  // 3. dw 3x3 conv + SiLU -> xc bf16
  conv2d_silu_kernel<<<TT * 48 / 256, 256, 0, stream>>>(xz0, conv2d_w, xc_bf);
  // 4. m_in_proj (MFMA): xc_bf @ W1 -> xz1 fp32 (18432x384)
  mfma_gemm_kernel<0, 0><<<dim3(TT / 128, 6), 256, 0, stream>>>(
      xc_bf, 192, Wt1, 192, xz1, 384, 384, 192, nullptr, 0);
  // 5. causal conv1d + bias + SiLU -> xmb fp32
  conv1d_silu_kernel<<<TT * 48 / 256, 256, 0, stream>>>(xz1, m_c1d_w, m_c1d_b, xmb);
  // 6. x_proj (fp32 vector): xmb @ W(192x44) -> xdbl
  gemm_f32_kernel<<<dim3(TT / 128, 1), 256, 0, stream>>>(xmb, 192, m_x_proj, 44, xdbl, 44, 44, 192);
  // 7. dt_proj + softplus -> dlt
  dtproj_kernel<<<TT * 192 / 256, 256, 0, stream>>>(xdbl, m_dt_w, m_dt_b, dlt);
  // 8. chunked selective scan
  scan1_kernel<<<BATCH * NCHUNK, 192, 0, stream>>>(dlt, xmb, xdbl, m_A_log, Pb, Eb);
  scan2a_kernel<<<BATCH * NSUP * QDN / 256, 256, 0, stream>>>(Pb, Eb, SPb, SEb);
  scan2b_kernel<<<BATCH * QDN / 256, 256, 0, stream>>>(SPb, SEb, Hsup);
  scan2c_kernel<<<BATCH * NSUP * QDN / 256, 256, 0, stream>>>(Pb, Eb, Hsup, Hin);
  scan3_kernel<<<BATCH * NCHUNK, 192, 0, stream>>>(dlt, xmb, xdbl, m_A_log, m_D, xz1, Hin, yfin);
  // 9. m_out_proj (MFMA) with silu(x_gate) epilogue -> yg bf16
  mfma_gemm_kernel<1, 1><<<dim3(TT / 128, 3), 256, 0, stream>>>(
      yfin, 192, Wt2, 192, yg, 192, 192, 192, xz0 + 192, 384);
  // 10. out_proj (MFMA) with residual epilogue -> out fp32
  mfma_gemm_kernel<2, 0><<<dim3(TT / 128, 2), 256, 0, stream>>>(
      yg, 192, Wt3, 192, out, 96, 96, 192, x, 96);
}

// Round 4
// 267.557 us; speedup vs baseline: 1.6536x; 1.0129x over previous
//
#include <hip/hip_runtime.h>

#define DEV_INLINE __device__ __forceinline__

constexpr int BATCH = 2;
constexpr int HH = 96, WW = 96, CC = 96;
constexpr int DI = 192;              // d_inner == mamba d_model
constexpr int NS = 16;               // d_state
constexpr int LSEQ = HH * WW;        // 9216
constexpr int TT = BATCH * LSEQ;     // 18432 tokens
constexpr int CHUNK = 32;            // scan chunk length
constexpr int NCHUNK = LSEQ / CHUNK; // 288 chunks per batch
constexpr int SUP = 24;              // chunks per super-chunk
constexpr int NSUP = NCHUNK / SUP;   // 12
constexpr int QDN = DI * NS;         // 3072

typedef __attribute__((ext_vector_type(8))) short bf16x8;
typedef __attribute__((ext_vector_type(4))) float f32x4;

DEV_INLINE float silu_f(float x) { return x / (1.f + __expf(-x)); }
DEV_INLINE float softplus_f(float x) {
  return fmaxf(x, 0.f) + log1pf(__expf(-fabsf(x)));
}
DEV_INLINE ushort f2bf(float f) {
  union { float f; unsigned u; } c; c.f = f;
  unsigned u = c.u + 0x7FFF + ((c.u >> 16) & 1);   // RNE
  return (ushort)(u >> 16);
}
DEV_INLINE float bf2f(ushort u) {
  union { unsigned u; float f; } c; c.u = ((unsigned)u) << 16; return c.f;
}

// ---------------- weight cast + transpose to bf16 [N][K] ----------------
// t0: in_proj  W[96 x384] -> [384][96]
// t1: m_in     W[192x384] -> [384][192]
// t2: m_out    W[192x192] -> [192][192]
// t3: out_proj W[192x 96] -> [128][192] (rows 96..127 zero)
// t4: x_proj   W[192x 44] -> Wxt[48][192], rows permuted: 0..15=B(12..27),
//              16..31=C(28..43), 32..43=dt(0..11), 44..47=zero
// t5: dt_proj  W[12 x192] -> Wdtt[192][32] (cols 12..31 zero)
__global__ __launch_bounds__(256)
void castw_kernel(const float* __restrict__ w0, const float* __restrict__ w1,
                  const float* __restrict__ w2, const float* __restrict__ w3,
                  const float* __restrict__ wx, const float* __restrict__ wdt,
                  ushort* __restrict__ t0, ushort* __restrict__ t1,
                  ushort* __restrict__ t2, ushort* __restrict__ t3,
                  ushort* __restrict__ t4, ushort* __restrict__ t5)
{
  int id = blockIdx.x * 256 + threadIdx.x;      // 187392 total
  if (id < 36864) {
    int k = id % 96, n = id / 96;
    t0[id] = f2bf(w0[k * 384 + n]);
  } else if (id < 110592) {
    int j = id - 36864; int k = j % 192, n = j / 192;
    t1[j] = f2bf(w1[k * 384 + n]);
  } else if (id < 147456) {
    int j = id - 110592; int k = j % 192, n = j / 192;
    t2[j] = f2bf(w2[k * 192 + n]);
  } else if (id < 172032) {
    int j = id - 147456; int k = j % 192, n = j / 192;
    t3[j] = (n < 96) ? f2bf(w3[k * 96 + n]) : (ushort)0;
  } else if (id < 181248) {
    int j = id - 172032; int k = j % 192, n = j / 192;    // Wxt[48][192]
    float v = 0.f;
    if (n < 16) v = wx[k * 44 + 12 + n];
    else if (n < 32) v = wx[k * 44 + 28 + (n - 16)];
    else if (n < 44) v = wx[k * 44 + (n - 32)];
    t4[j] = f2bf(v);
  } else {
    int j = id - 181248; int r = j % 32, d = j / 32;      // Wdtt[192][32]
    t5[j] = (r < 12) ? f2bf(wdt[r * 192 + d]) : (ushort)0;
  }
}

// ---------------- LayerNorm over C=96 -> bf16, one wave per token ----------------
__global__ __launch_bounds__(256)
void ln_kernel(const float* __restrict__ x, const float* __restrict__ w,
               const float* __restrict__ bb, ushort* __restrict__ xn)
{
  int wid = (blockIdx.x * blockDim.x + threadIdx.x) >> 6;  // token
  int lane = threadIdx.x & 63;
  if (wid >= TT) return;
  const float* xr = x + (size_t)wid * CC;
  float v0 = xr[lane];
  float v1 = (lane < 32) ? xr[64 + lane] : 0.f;
  float s = v0 + v1, ss = v0 * v0 + v1 * v1;
#pragma unroll
  for (int off = 32; off >= 1; off >>= 1) {
    s  += __shfl_xor(s, off);
    ss += __shfl_xor(ss, off);
  }
  float mean = s * (1.f / 96.f);
  float var  = ss * (1.f / 96.f) - mean * mean;
  float rstd = rsqrtf(var + 1e-5f);
  ushort* o = xn + (size_t)wid * CC;
  o[lane] = f2bf((v0 - mean) * rstd * w[lane] + bb[lane]);
  if (lane < 32) o[64 + lane] = f2bf((v1 - mean) * rstd * w[64 + lane] + bb[64 + lane]);
}

// ---------------- bf16 MFMA GEMM, swapped-operand (lane owns token, regs own 4 cols) ----
// A row-major bf16 [M x K] (tokens); Bt = W^T bf16 [Npad x K].
// Block 256 = 4 waves (2x2); block tile 128 tok x 64 n; wave tile 64 x 32.
// EPI: 0 none, 1 mul silu(aux bf16), 2 add aux fp32.  OUTF: 0 fp32, 1 bf16.
template<int EPI, int OUTF>
__global__ __launch_bounds__(256)
void mfma_gemm_kernel(const ushort* __restrict__ A, int lda,
                      const ushort* __restrict__ Bt, int ldb,
                      void* __restrict__ Cout, int ldc, int N, int K,
                      const void* __restrict__ aux, int ldaux)
{
  const int tid = threadIdx.x;
  const int wid = tid >> 6, lane = tid & 63;
  const int wm = wid >> 1, wn = wid & 1;
  const int m0 = blockIdx.x * 128 + wm * 64;
  const int n0 = blockIdx.y * 64 + wn * 32;
  const int l16 = lane & 15, quad = lane >> 4;

  f32x4 acc[4][2];
  const f32x4 z4 = {0.f, 0.f, 0.f, 0.f};
#pragma unroll
  for (int i = 0; i < 4; ++i)
#pragma unroll
    for (int j = 0; j < 2; ++j) acc[i][j] = z4;

  for (int k0 = 0; k0 < K; k0 += 32) {
    bf16x8 xf[4], wf[2];
#pragma unroll
    for (int i = 0; i < 4; ++i)
      xf[i] = *(const bf16x8*)(A + (size_t)(m0 + i * 16 + l16) * lda + k0 + quad * 8);
#pragma unroll
    for (int j = 0; j < 2; ++j)
      wf[j] = *(const bf16x8*)(Bt + (size_t)(n0 + j * 16 + l16) * ldb + k0 + quad * 8);
#pragma unroll
    for (int i = 0; i < 4; ++i)
#pragma unroll
      for (int j = 0; j < 2; ++j)
        acc[i][j] = __builtin_amdgcn_mfma_f32_16x16x32_bf16(wf[j], xf[i], acc[i][j], 0, 0, 0);
  }

#pragma unroll
  for (int i = 0; i < 4; ++i) {
    const int token = m0 + i * 16 + l16;
#pragma unroll
    for (int j = 0; j < 2; ++j) {
      const int nb = n0 + j * 16 + quad * 4;
      if (nb >= N) continue;
      float v[4];
#pragma unroll
      for (int r = 0; r < 4; ++r) v[r] = acc[i][j][r];
      if (EPI == 1) {
        const ushort4 g4 = *(const ushort4*)((const ushort*)aux + (size_t)token * ldaux + nb);
        v[0] *= silu_f(bf2f(g4.x)); v[1] *= silu_f(bf2f(g4.y));
        v[2] *= silu_f(bf2f(g4.z)); v[3] *= silu_f(bf2f(g4.w));
      } else if (EPI == 2) {
        const float4 r4 = *(const float4*)((const float*)aux + (size_t)token * ldaux + nb);
        v[0] += r4.x; v[1] += r4.y; v[2] += r4.z; v[3] += r4.w;
      }
      if (OUTF == 0) {
        *(float4*)((float*)Cout + (size_t)token * ldc + nb) =
            make_float4(v[0], v[1], v[2], v[3]);
      } else {
        ushort4 o;
        o.x = f2bf(v[0]); o.y = f2bf(v[1]); o.z = f2bf(v[2]); o.w = f2bf(v[3]);
        *(ushort4*)((ushort*)Cout + (size_t)token * ldc + nb) = o;
      }
    }
  }
}

// ---------------- depthwise 3x3 conv + SiLU, bf16 in/out (channels-last) ----------------
__global__ __launch_bounds__(256)
void conv2d_silu_kernel(const ushort* __restrict__ xz0, const float* __restrict__ w,
                        ushort* __restrict__ xc)
{
  __shared__ float ws[DI * 9];
  for (int i = threadIdx.x; i < DI * 9; i += 256) ws[i] = w[i];
  __syncthreads();
  int id = blockIdx.x * 256 + threadIdx.x;     // TT*48
  int dq = id % 48;
  int p  = id / 48;
  int j = p % WW;
  int i = (p / WW) % HH;
  int b = p / (WW * HH);
  int d = dq * 4;
  float a0 = 0.f, a1 = 0.f, a2 = 0.f, a3 = 0.f;
#pragma unroll
  for (int ki = 0; ki < 3; ++ki) {
    int ii = i + ki - 1;
    if (ii < 0 || ii >= HH) continue;
#pragma unroll
    for (int kj = 0; kj < 3; ++kj) {
      int jj = j + kj - 1;
      if (jj < 0 || jj >= WW) continue;
      const ushort4 v = *(const ushort4*)(xz0 + ((size_t)((b * HH + ii) * WW + jj)) * 384 + d);
      int wk = ki * 3 + kj;
      a0 = fmaf(bf2f(v.x), ws[(d + 0) * 9 + wk], a0);
      a1 = fmaf(bf2f(v.y), ws[(d + 1) * 9 + wk], a1);
      a2 = fmaf(bf2f(v.z), ws[(d + 2) * 9 + wk], a2);
      a3 = fmaf(bf2f(v.w), ws[(d + 3) * 9 + wk], a3);
    }
  }
  ushort4 o;
  o.x = f2bf(silu_f(a0)); o.y = f2bf(silu_f(a1));
  o.z = f2bf(silu_f(a2)); o.w = f2bf(silu_f(a3));
  *(ushort4*)(xc + (size_t)p * DI + d) = o;
}

// ---------------- fused mamba prep: conv1d+SiLU, x_proj (MFMA), dt_proj (MFMA)+softplus --
// Block: 64 tokens, 256 threads (4 waves; wave w owns 16-token strip).
// Outputs: xmb_bf [TT][192] bf16 (u), xdbl_bc [TT][32] fp32 (B|C), dlt [TT][192] fp32.
__global__ __launch_bounds__(256)
void mamba_prep_kernel(const ushort* __restrict__ xz1, const float* __restrict__ cw,
                       const float* __restrict__ cb, const ushort* __restrict__ Wxt,
                       const ushort* __restrict__ Wdtt, const float* __restrict__ bdt,
                       ushort* __restrict__ xmb_bf, float* __restrict__ xdbl_bc,
                       float* __restrict__ dlt)
{
  __shared__ ushort sxm[64][200];   // +8 pad: row stride 400 B (100 dw) kills bank conflicts
  __shared__ ushort sdtb[64][40];   // dt staged bf16, K-padded to 32 (cols 32..39 unused)
  const int tid = threadIdx.x;
  const int t0 = blockIdx.x * 64;
  const int l0 = t0 % LSEQ;

  for (int i = tid; i < 64 * 40 / 2; i += 256) ((unsigned*)sdtb)[i] = 0;

  // causal depthwise conv1d (k=3) + bias + SiLU -> sxm (bf16) + global xmb_bf
#pragma unroll
  for (int it = 0; it < 12; ++it) {
    int task = tid + it * 256;           // 3072 = 64 tokens * 48 d-quads
    int dq = task % 48, tl = task / 48;
    int d = dq * 4;
    int t = t0 + tl, l = l0 + tl;
    float a0 = cb[d], a1 = cb[d + 1], a2 = cb[d + 2], a3 = cb[d + 3];
#pragma unroll
    for (int k = 0; k < 3; ++k) {
      if (l + k - 2 < 0) continue;
      const ushort4 v = *(const ushort4*)(xz1 + (size_t)(t + k - 2) * 384 + d);
      a0 = fmaf(bf2f(v.x), cw[(d + 0) * 3 + k], a0);
      a1 = fmaf(bf2f(v.y), cw[(d + 1) * 3 + k], a1);
      a2 = fmaf(bf2f(v.z), cw[(d + 2) * 3 + k], a2);
      a3 = fmaf(bf2f(v.w), cw[(d + 3) * 3 + k], a3);
    }
    ushort4 o;
    o.x = f2bf(silu_f(a0)); o.y = f2bf(silu_f(a1));
    o.z = f2bf(silu_f(a2)); o.w = f2bf(silu_f(a3));
    *(ushort4*)&sxm[tl][d] = o;
    *(ushort4*)(xmb_bf + (size_t)t * DI + d) = o;
  }
  __syncthreads();

  const int wid = tid >> 6, lane = tid & 63;
  const int l16 = lane & 15, quad = lane >> 4;
  const int ts = wid * 16;                 // strip token base (local)
  const int token = t0 + ts + l16;         // this lane's token (swapped-operand layout)
  const f32x4 z4 = {0.f, 0.f, 0.f, 0.f};

  // MFMA stage 1: x_dbl[64 x 48] = xm @ Wx  (tiles: 0=B, 1=C, 2=dt)
  f32x4 acc1[3] = {z4, z4, z4};
  for (int k0 = 0; k0 < 192; k0 += 32) {
    bf16x8 xf = *(const bf16x8*)&sxm[ts + l16][k0 + quad * 8];
#pragma unroll
    for (int j = 0; j < 3; ++j) {
      bf16x8 wf = *(const bf16x8*)(Wxt + (size_t)(j * 16 + l16) * 192 + k0 + quad * 8);
      acc1[j] = __builtin_amdgcn_mfma_f32_16x16x32_bf16(wf, xf, acc1[j], 0, 0, 0);
    }
  }
#pragma unroll
  for (int j = 0; j < 2; ++j)    // B, C -> global fp32
    *(float4*)(xdbl_bc + (size_t)token * 32 + j * 16 + quad * 4) =
        make_float4(acc1[j][0], acc1[j][1], acc1[j][2], acc1[j][3]);
  if (quad < 3) {                 // dt cols 0..11 -> LDS bf16 (rest stays zero)
    ushort4 o;
    o.x = f2bf(acc1[2][0]); o.y = f2bf(acc1[2][1]);
    o.z = f2bf(acc1[2][2]); o.w = f2bf(acc1[2][3]);
    *(ushort4*)&sdtb[ts + l16][quad * 4] = o;
  }
  __syncthreads();

  // MFMA stage 2: delta[64 x 192] = softplus(dt @ Wdt + bdt)
  bf16x8 dtf = *(const bf16x8*)&sdtb[ts + l16][quad * 8];
  f32x4 acc2[12];
#pragma unroll
  for (int jj = 0; jj < 12; ++jj) {
    bf16x8 wf = *(const bf16x8*)(Wdtt + (size_t)(jj * 16 + l16) * 32 + quad * 8);
    acc2[jj] = __builtin_amdgcn_mfma_f32_16x16x32_bf16(wf, dtf, z4, 0, 0, 0);
  }
#pragma unroll
  for (int jj = 0; jj < 12; ++jj) {
    const int nb = jj * 16 + quad * 4;
    float4 dv;
    dv.x = softplus_f(acc2[jj][0] + bdt[nb + 0]);
    dv.y = softplus_f(acc2[jj][1] + bdt[nb + 1]);
    dv.z = softplus_f(acc2[jj][2] + bdt[nb + 2]);
    dv.w = softplus_f(acc2[jj][3] + bdt[nb + 3]);
    *(float4*)(dlt + (size_t)token * DI + nb) = dv;
  }
}

// ---------------- selective scan: thread = (b, chunk, d), 16 n-states in regs ----------------
__global__ __launch_bounds__(192)
void scan1_kernel(const float* __restrict__ dlt, const ushort* __restrict__ xmb,
                  const float* __restrict__ xdbl_bc, const float* __restrict__ Alog,
                  float* __restrict__ P, float* __restrict__ E)
{
  const int d = threadIdx.x;               // 0..191
  const int g = blockIdx.x % NCHUNK;
  const int b = blockIdx.x / NCHUNK;
  const int t0 = b * LSEQ + g * CHUNK;
  float Av[16];
#pragma unroll
  for (int j = 0; j < 16; ++j) Av[j] = -__expf(Alog[d * 16 + j]);
  float e[16];
#pragma unroll
  for (int j = 0; j < 16; ++j) e[j] = 0.f;
  float sdl = 0.f;
#pragma unroll 2
  for (int l = 0; l < CHUNK; ++l) {
    const int t = t0 + l;
    float dl = dlt[(size_t)t * DI + d];
    float u  = bf2f(xmb[(size_t)t * DI + d]);
    const float4 B0 = *(const float4*)(xdbl_bc + (size_t)t * 32 + 0);
    const float4 B1 = *(const float4*)(xdbl_bc + (size_t)t * 32 + 4);
    const float4 B2 = *(const float4*)(xdbl_bc + (size_t)t * 32 + 8);
    const float4 B3 = *(const float4*)(xdbl_bc + (size_t)t * 32 + 12);
    const float Bv[16] = {B0.x, B0.y, B0.z, B0.w, B1.x, B1.y, B1.z, B1.w,
                          B2.x, B2.y, B2.z, B2.w, B3.x, B3.y, B3.z, B3.w};
    float du = dl * u;
    sdl += dl;
#pragma unroll
    for (int j = 0; j < 16; ++j) {
      float a = __expf(dl * Av[j]);
      e[j] = fmaf(a, e[j], du * Bv[j]);
    }
  }
  size_t base = ((size_t)(b * NCHUNK + g)) * QDN + d * 16;
#pragma unroll
  for (int j = 0; j < 16; ++j) {
    P[base + j] = __expf(Av[j] * sdl);
    E[base + j] = e[j];
  }
}

// level-2a: per super-chunk product/accum over SUP chunks
__global__ __launch_bounds__(256)
void scan2a_kernel(const float* __restrict__ P, const float* __restrict__ E,
                   float* __restrict__ SP, float* __restrict__ SE)
{
  int id = blockIdx.x * 256 + threadIdx.x;  // BATCH*NSUP*QDN = 73728
  int q = id % QDN;
  int s = (id / QDN) % NSUP;
  int b = id / (QDN * NSUP);
  float cp = 1.f, ce = 0.f;
#pragma unroll 4
  for (int c = 0; c < SUP; ++c) {
    size_t idx = ((size_t)(b * NCHUNK + s * SUP + c)) * QDN + q;
    float p = P[idx], e = E[idx];
    ce = fmaf(p, ce, e);
    cp *= p;
  }
  SP[id] = cp; SE[id] = ce;
}

// level-2b: serial scan over NSUP super-chunks
__global__ __launch_bounds__(256)
void scan2b_kernel(const float* __restrict__ SP, const float* __restrict__ SE,
                   float* __restrict__ Hsup)
{
  int id = blockIdx.x * 256 + threadIdx.x;  // BATCH*QDN = 6144
  int q = id % QDN;
  int b = id / QDN;
  float carry = 0.f;
#pragma unroll
  for (int s = 0; s < NSUP; ++s) {
    size_t idx = ((size_t)(b * NSUP + s)) * QDN + q;
    Hsup[idx] = carry;
    carry = fmaf(SP[idx], carry, SE[idx]);
  }
}

// level-2c: expand to per-chunk inbound states
__global__ __launch_bounds__(256)
void scan2c_kernel(const float* __restrict__ P, const float* __restrict__ E,
                   const float* __restrict__ Hsup, float* __restrict__ Hin)
{
  int id = blockIdx.x * 256 + threadIdx.x;  // 73728
  int q = id % QDN;
  int s = (id / QDN) % NSUP;
  int b = id / (QDN * NSUP);
  float h = Hsup[id];
#pragma unroll 4
  for (int c = 0; c < SUP; ++c) {
    size_t idx = ((size_t)(b * NCHUNK + s * SUP + c)) * QDN + q;
    Hin[idx] = h;
    h = fmaf(P[idx], h, E[idx]);
  }
}

// phase3: replay chunk, y = (sum_n h*C + u*D) * silu(z) -> bf16
__global__ __launch_bounds__(192)
void scan3_kernel(const float* __restrict__ dlt, const ushort* __restrict__ xmb,
                  const float* __restrict__ xdbl_bc, const float* __restrict__ Alog,
                  const float* __restrict__ Dv, const ushort* __restrict__ xz1,
                  const float* __restrict__ Hin, ushort* __restrict__ yout)
{
  const int d = threadIdx.x;
  const int g = blockIdx.x % NCHUNK;
  const int b = blockIdx.x / NCHUNK;
  const int t0 = b * LSEQ + g * CHUNK;
  float Av[16];
#pragma unroll
  for (int j = 0; j < 16; ++j) Av[j] = -__expf(Alog[d * 16 + j]);
  const float Dd = Dv[d];
  float h[16];
  {
    size_t hb = ((size_t)(b * NCHUNK + g)) * QDN + d * 16;
#pragma unroll
    for (int j = 0; j < 16; ++j) h[j] = Hin[hb + j];
  }
#pragma unroll 2
  for (int l = 0; l < CHUNK; ++l) {
    const int t = t0 + l;
    float dl = dlt[(size_t)t * DI + d];
    float u  = bf2f(xmb[(size_t)t * DI + d]);
    const float4 B0 = *(const float4*)(xdbl_bc + (size_t)t * 32 + 0);
    const float4 B1 = *(const float4*)(xdbl_bc + (size_t)t * 32 + 4);
    const float4 B2 = *(const float4*)(xdbl_bc + (size_t)t * 32 + 8);
    const float4 B3 = *(const float4*)(xdbl_bc + (size_t)t * 32 + 12);
    const float4 C0 = *(const float4*)(xdbl_bc + (size_t)t * 32 + 16);
    const float4 C1 = *(const float4*)(xdbl_bc + (size_t)t * 32 + 20);
    const float4 C2 = *(const float4*)(xdbl_bc + (size_t)t * 32 + 24);
    const float4 C3 = *(const float4*)(xdbl_bc + (size_t)t * 32 + 28);
    const float Bv[16] = {B0.x, B0.y, B0.z, B0.w, B1.x, B1.y, B1.z, B1.w,
                          B2.x, B2.y, B2.z, B2.w, B3.x, B3.y, B3.z, B3.w};
    const float Cv[16] = {C0.x, C0.y, C0.z, C0.w, C1.x, C1.y, C1.z, C1.w,
                          C2.x, C2.y, C2.z, C2.w, C3.x, C3.y, C3.z, C3.w};
    float du = dl * u;
    float y0 = 0.f, y1 = 0.f, y2 = 0.f, y3 = 0.f;
#pragma unroll
    for (int j = 0; j < 16; ++j) {
      float a = __expf(dl * Av[j]);
      h[j] = fmaf(a, h[j], du * Bv[j]);
      if ((j & 3) == 0) y0 = fmaf(h[j], Cv[j], y0);
      else if ((j & 3) == 1) y1 = fmaf(h[j], Cv[j], y1);
      else if ((j & 3) == 2) y2 = fmaf(h[j], Cv[j], y2);
      else y3 = fmaf(h[j], Cv[j], y3);
    }
    float y = (y0 + y1) + (y2 + y3) + u * Dd;
    float z = bf2f(xz1[(size_t)t * 384 + 192 + d]);
    yout[(size_t)t * DI + d] = f2bf(y * silu_f(z));
  }
}

// ---------------- launch ----------------
extern "C" void kernel_launch(void* const* d_in, const int* in_sizes, int n_in,
                              void* d_out, int out_size, void* d_ws, size_t ws_size,
                              hipStream_t stream)
{
  const float* x         = (const float*)d_in[0];
  const float* norm_w    = (const float*)d_in[1];
  const float* norm_b    = (const float*)d_in[2];
  const float* in_proj_w = (const float*)d_in[3];
  const float* conv2d_w  = (const float*)d_in[4];
  const float* m_in_proj = (const float*)d_in[5];
  const float* m_c1d_w   = (const float*)d_in[6];
  const float* m_c1d_b   = (const float*)d_in[7];
  const float* m_x_proj  = (const float*)d_in[8];
  const float* m_dt_w    = (const float*)d_in[9];
  const float* m_dt_b    = (const float*)d_in[10];
  const float* m_A_log   = (const float*)d_in[11];
  const float* m_D       = (const float*)d_in[12];
  const float* m_out_w   = (const float*)d_in[13];
  const float* out_w     = (const float*)d_in[14];
  float* out = (float*)d_out;

  char* wp = (char*)d_ws;
  auto alloc = [&](size_t bytes) {
    char* r = wp; wp += (bytes + 255) & ~(size_t)255; return r;
  };
  ushort* Wt0    = (ushort*)alloc(36864 * 2);      // [384][96]
  ushort* Wt1    = (ushort*)alloc(73728 * 2);      // [384][192]
  ushort* Wt2    = (ushort*)alloc(36864 * 2);      // [192][192]
  ushort* Wt3    = (ushort*)alloc(24576 * 2);      // [128][192]
  ushort* Wxt    = (ushort*)alloc(9216 * 2);       // [48][192]
  ushort* Wdtt   = (ushort*)alloc(6144 * 2);       // [192][32]
  ushort* xn_bf  = (ushort*)alloc((size_t)TT * 96 * 2);
  ushort* xz0    = (ushort*)alloc((size_t)TT * 384 * 2);   // x_in | gate (bf16)
  ushort* xc_bf  = (ushort*)alloc((size_t)TT * 192 * 2);
  ushort* xz1    = (ushort*)alloc((size_t)TT * 384 * 2);   // xm_pre | z (bf16)
  ushort* xmb_bf = (ushort*)alloc((size_t)TT * 192 * 2);
  float*  xdbl_bc= (float*)alloc((size_t)TT * 32 * 4);     // B | C (fp32)
  float*  dlt    = (float*)alloc((size_t)TT * 192 * 4);
  float*  Pb     = (float*)alloc((size_t)BATCH * NCHUNK * QDN * 4);
  float*  Eb     = (float*)alloc((size_t)BATCH * NCHUNK * QDN * 4);
  float*  Hin    = (float*)alloc((size_t)BATCH * NCHUNK * QDN * 4);
  float*  SPb    = (float*)alloc((size_t)BATCH * NSUP * QDN * 4);
  float*  SEb    = (float*)alloc((size_t)BATCH * NSUP * QDN * 4);
  float*  Hsup   = (float*)alloc((size_t)BATCH * NSUP * QDN * 4);
  ushort* yfin   = (ushort*)alloc((size_t)TT * 192 * 2);
  ushort* yg     = (ushort*)alloc((size_t)TT * 192 * 2);

  // 0. weight cast/transpose/permute
  castw_kernel<<<732, 256, 0, stream>>>(in_proj_w, m_in_proj, m_out_w, out_w,
                                        m_x_proj, m_dt_w,
                                        Wt0, Wt1, Wt2, Wt3, Wxt, Wdtt);
  // 1. LayerNorm -> bf16
  ln_kernel<<<TT / 4, 256, 0, stream>>>(x, norm_w, norm_b, xn_bf);
  // 2. in_proj (MFMA): -> xz0 bf16 (18432x384)
  mfma_gemm_kernel<0, 1><<<dim3(TT / 128, 6), 256, 0, stream>>>(
      xn_bf, 96, Wt0, 96, xz0, 384, 384, 96, nullptr, 0);
  // 3. dw 3x3 conv + SiLU -> xc bf16
  conv2d_silu_kernel<<<TT * 48 / 256, 256, 0, stream>>>(xz0, conv2d_w, xc_bf);
  // 4. m_in_proj (MFMA): -> xz1 bf16 (18432x384)
  mfma_gemm_kernel<0, 1><<<dim3(TT / 128, 6), 256, 0, stream>>>(
      xc_bf, 192, Wt1, 192, xz1, 384, 384, 192, nullptr, 0);
  // 5. fused conv1d + x_proj + dt_proj -> xmb_bf, xdbl_bc, dlt
  mamba_prep_kernel<<<TT / 64, 256, 0, stream>>>(
      xz1, m_c1d_w, m_c1d_b, Wxt, Wdtt, m_dt_b, xmb_bf, xdbl_bc, dlt);
  // 6. chunked selective scan
  scan1_kernel<<<BATCH * NCHUNK, 192, 0, stream>>>(dlt, xmb_bf, xdbl_bc, m_A_log, Pb, Eb);
  scan2a_kernel<<<BATCH * NSUP * QDN / 256, 256, 0, stream>>>(Pb, Eb, SPb, SEb);
  scan2b_kernel<<<BATCH * QDN / 256, 256, 0, stream>>>(SPb, SEb, Hsup);
  scan2c_kernel<<<BATCH * NSUP * QDN / 256, 256, 0, stream>>>(Pb, Eb, Hsup, Hin);
  scan3_kernel<<<BATCH * NCHUNK, 192, 0, stream>>>(dlt, xmb_bf, xdbl_bc, m_A_log, m_D, xz1, Hin, yfin);
  // 7. m_out_proj (MFMA) with silu(gate) epilogue -> yg bf16
  mfma_gemm_kernel<1, 1><<<dim3(TT / 128, 3), 256, 0, stream>>>(
      yfin, 192, Wt2, 192, yg, 192, 192, 192, xz0 + 192, 384);
  // 8. out_proj (MFMA) with residual epilogue -> out fp32
  mfma_gemm_kernel<2, 0><<<dim3(TT / 128, 2), 256, 0, stream>>>(
      yg, 192, Wt3, 192, out, 96, 96, 192, x, 96);
}

// Round 5
// 260.312 us; speedup vs baseline: 1.6996x; 1.0278x over previous
//
#include <hip/hip_runtime.h>

#define DEV_INLINE __device__ __forceinline__

constexpr int BATCH = 2;
constexpr int HH = 96, WW = 96, CC = 96;
constexpr int DI = 192;              // d_inner == mamba d_model
constexpr int NS = 16;               // d_state
constexpr int LSEQ = HH * WW;        // 9216
constexpr int TT = BATCH * LSEQ;     // 18432 tokens
constexpr int CHUNK = 32;            // scan chunk length
constexpr int NCHUNK = LSEQ / CHUNK; // 288 chunks per batch
constexpr int SUP = 24;              // chunks per super-chunk
constexpr int NSUP = NCHUNK / SUP;   // 12
constexpr int QDN = DI * NS;         // 3072

typedef __attribute__((ext_vector_type(8))) short bf16x8;
typedef __attribute__((ext_vector_type(4))) float f32x4;

DEV_INLINE float silu_f(float x) { return x / (1.f + __expf(-x)); }
DEV_INLINE float softplus_f(float x) {
  return fmaxf(x, 0.f) + log1pf(__expf(-fabsf(x)));
}
DEV_INLINE ushort f2bf(float f) {
  union { float f; unsigned u; } c; c.f = f;
  unsigned u = c.u + 0x7FFF + ((c.u >> 16) & 1);   // RNE
  return (ushort)(u >> 16);
}
DEV_INLINE float bf2f(ushort u) {
  union { unsigned u; float f; } c; c.u = ((unsigned)u) << 16; return c.f;
}

// ---------------- weight cast + transpose to bf16 [N][K] ----------------
// t0: in_proj  W[96 x384] -> [384][96]
// t1: m_in     W[192x384] -> [384][192]
// t2: m_out    W[192x192] -> [192][192]
// t3: out_proj W[192x 96] -> [128][192] (rows 96..127 zero)
// t4: x_proj   W[192x 44] -> Wxt[48][192], rows permuted: 0..15=B(12..27),
//              16..31=C(28..43), 32..43=dt(0..11), 44..47=zero
// t5: dt_proj  W[12 x192] -> Wdtt[192][32] (cols 12..31 zero)
__global__ __launch_bounds__(256)
void castw_kernel(const float* __restrict__ w0, const float* __restrict__ w1,
                  const float* __restrict__ w2, const float* __restrict__ w3,
                  const float* __restrict__ wx, const float* __restrict__ wdt,
                  ushort* __restrict__ t0, ushort* __restrict__ t1,
                  ushort* __restrict__ t2, ushort* __restrict__ t3,
                  ushort* __restrict__ t4, ushort* __restrict__ t5)
{
  int id = blockIdx.x * 256 + threadIdx.x;      // 187392 total
  if (id < 36864) {
    int k = id % 96, n = id / 96;
    t0[id] = f2bf(w0[k * 384 + n]);
  } else if (id < 110592) {
    int j = id - 36864; int k = j % 192, n = j / 192;
    t1[j] = f2bf(w1[k * 384 + n]);
  } else if (id < 147456) {
    int j = id - 110592; int k = j % 192, n = j / 192;
    t2[j] = f2bf(w2[k * 192 + n]);
  } else if (id < 172032) {
    int j = id - 147456; int k = j % 192, n = j / 192;
    t3[j] = (n < 96) ? f2bf(w3[k * 96 + n]) : (ushort)0;
  } else if (id < 181248) {
    int j = id - 172032; int k = j % 192, n = j / 192;    // Wxt[48][192]
    float v = 0.f;
    if (n < 16) v = wx[k * 44 + 12 + n];
    else if (n < 32) v = wx[k * 44 + 28 + (n - 16)];
    else if (n < 44) v = wx[k * 44 + (n - 32)];
    t4[j] = f2bf(v);
  } else {
    int j = id - 181248; int r = j % 32, d = j / 32;      // Wdtt[192][32]
    t5[j] = (r < 12) ? f2bf(wdt[r * 192 + d]) : (ushort)0;
  }
}

// ---------------- LayerNorm over C=96 -> bf16, one wave per token ----------------
__global__ __launch_bounds__(256)
void ln_kernel(const float* __restrict__ x, const float* __restrict__ w,
               const float* __restrict__ bb, ushort* __restrict__ xn)
{
  int wid = (blockIdx.x * blockDim.x + threadIdx.x) >> 6;  // token
  int lane = threadIdx.x & 63;
  if (wid >= TT) return;
  const float* xr = x + (size_t)wid * CC;
  float v0 = xr[lane];
  float v1 = (lane < 32) ? xr[64 + lane] : 0.f;
  float s = v0 + v1, ss = v0 * v0 + v1 * v1;
#pragma unroll
  for (int off = 32; off >= 1; off >>= 1) {
    s  += __shfl_xor(s, off);
    ss += __shfl_xor(ss, off);
  }
  float mean = s * (1.f / 96.f);
  float var  = ss * (1.f / 96.f) - mean * mean;
  float rstd = rsqrtf(var + 1e-5f);
  ushort* o = xn + (size_t)wid * CC;
  o[lane] = f2bf((v0 - mean) * rstd * w[lane] + bb[lane]);
  if (lane < 32) o[64 + lane] = f2bf((v1 - mean) * rstd * w[64 + lane] + bb[64 + lane]);
}

// ---------------- bf16 MFMA GEMM, swapped-operand (lane owns token, regs own 4 cols) ----
// A row-major bf16 [M x K] (tokens); Bt = W^T bf16 [Npad x K].
// Block 256 = 4 waves (2x2); block tile 128 tok x 64 n; wave tile 64 x 32.
// EPI: 0 none, 1 mul silu(aux bf16), 2 add aux fp32.  OUTF: 0 fp32, 1 bf16.
template<int EPI, int OUTF>
__global__ __launch_bounds__(256)
void mfma_gemm_kernel(const ushort* __restrict__ A, int lda,
                      const ushort* __restrict__ Bt, int ldb,
                      void* __restrict__ Cout, int ldc, int N, int K,
                      const void* __restrict__ aux, int ldaux)
{
  const int tid = threadIdx.x;
  const int wid = tid >> 6, lane = tid & 63;
  const int wm = wid >> 1, wn = wid & 1;
  const int m0 = blockIdx.x * 128 + wm * 64;
  const int n0 = blockIdx.y * 64 + wn * 32;
  const int l16 = lane & 15, quad = lane >> 4;

  f32x4 acc[4][2];
  const f32x4 z4 = {0.f, 0.f, 0.f, 0.f};
#pragma unroll
  for (int i = 0; i < 4; ++i)
#pragma unroll
    for (int j = 0; j < 2; ++j) acc[i][j] = z4;

  for (int k0 = 0; k0 < K; k0 += 32) {
    bf16x8 xf[4], wf[2];
#pragma unroll
    for (int i = 0; i < 4; ++i)
      xf[i] = *(const bf16x8*)(A + (size_t)(m0 + i * 16 + l16) * lda + k0 + quad * 8);
#pragma unroll
    for (int j = 0; j < 2; ++j)
      wf[j] = *(const bf16x8*)(Bt + (size_t)(n0 + j * 16 + l16) * ldb + k0 + quad * 8);
#pragma unroll
    for (int i = 0; i < 4; ++i)
#pragma unroll
      for (int j = 0; j < 2; ++j)
        acc[i][j] = __builtin_amdgcn_mfma_f32_16x16x32_bf16(wf[j], xf[i], acc[i][j], 0, 0, 0);
  }

#pragma unroll
  for (int i = 0; i < 4; ++i) {
    const int token = m0 + i * 16 + l16;
#pragma unroll
    for (int j = 0; j < 2; ++j) {
      const int nb = n0 + j * 16 + quad * 4;
      if (nb >= N) continue;
      float v[4];
#pragma unroll
      for (int r = 0; r < 4; ++r) v[r] = acc[i][j][r];
      if (EPI == 1) {
        const ushort4 g4 = *(const ushort4*)((const ushort*)aux + (size_t)token * ldaux + nb);
        v[0] *= silu_f(bf2f(g4.x)); v[1] *= silu_f(bf2f(g4.y));
        v[2] *= silu_f(bf2f(g4.z)); v[3] *= silu_f(bf2f(g4.w));
      } else if (EPI == 2) {
        const float4 r4 = *(const float4*)((const float*)aux + (size_t)token * ldaux + nb);
        v[0] += r4.x; v[1] += r4.y; v[2] += r4.z; v[3] += r4.w;
      }
      if (OUTF == 0) {
        *(float4*)((float*)Cout + (size_t)token * ldc + nb) =
            make_float4(v[0], v[1], v[2], v[3]);
      } else {
        ushort4 o;
        o.x = f2bf(v[0]); o.y = f2bf(v[1]); o.z = f2bf(v[2]); o.w = f2bf(v[3]);
        *(ushort4*)((ushort*)Cout + (size_t)token * ldc + nb) = o;
      }
    }
  }
}

// ---------------- depthwise 3x3 conv + SiLU, bf16 in/out (channels-last) ----------------
__global__ __launch_bounds__(256)
void conv2d_silu_kernel(const ushort* __restrict__ xz0, const float* __restrict__ w,
                        ushort* __restrict__ xc)
{
  __shared__ float ws[DI * 9];
  for (int i = threadIdx.x; i < DI * 9; i += 256) ws[i] = w[i];
  __syncthreads();
  int id = blockIdx.x * 256 + threadIdx.x;     // TT*48
  int dq = id % 48;
  int p  = id / 48;
  int j = p % WW;
  int i = (p / WW) % HH;
  int b = p / (WW * HH);
  int d = dq * 4;
  float a0 = 0.f, a1 = 0.f, a2 = 0.f, a3 = 0.f;
#pragma unroll
  for (int ki = 0; ki < 3; ++ki) {
    int ii = i + ki - 1;
    if (ii < 0 || ii >= HH) continue;
#pragma unroll
    for (int kj = 0; kj < 3; ++kj) {
      int jj = j + kj - 1;
      if (jj < 0 || jj >= WW) continue;
      const ushort4 v = *(const ushort4*)(xz0 + ((size_t)((b * HH + ii) * WW + jj)) * 384 + d);
      int wk = ki * 3 + kj;
      a0 = fmaf(bf2f(v.x), ws[(d + 0) * 9 + wk], a0);
      a1 = fmaf(bf2f(v.y), ws[(d + 1) * 9 + wk], a1);
      a2 = fmaf(bf2f(v.z), ws[(d + 2) * 9 + wk], a2);
      a3 = fmaf(bf2f(v.w), ws[(d + 3) * 9 + wk], a3);
    }
  }
  ushort4 o;
  o.x = f2bf(silu_f(a0)); o.y = f2bf(silu_f(a1));
  o.z = f2bf(silu_f(a2)); o.w = f2bf(silu_f(a3));
  *(ushort4*)(xc + (size_t)p * DI + d) = o;
}

// ---------------- causal depthwise conv1d (k=3) + bias + SiLU, bf16 in/out -------------
__global__ __launch_bounds__(256)
void conv1d_silu_kernel(const ushort* __restrict__ xz1, const float* __restrict__ w,
                        const float* __restrict__ bias, ushort* __restrict__ xm)
{
  int id = blockIdx.x * 256 + threadIdx.x;   // TT*48
  int dq = id % 48;
  int t  = id / 48;
  int l  = t % LSEQ;
  int d  = dq * 4;
  float a0 = bias[d + 0], a1 = bias[d + 1], a2 = bias[d + 2], a3 = bias[d + 3];
#pragma unroll
  for (int k = 0; k < 3; ++k) {
    if (l + k - 2 < 0) continue;
    const ushort4 v = *(const ushort4*)(xz1 + (size_t)(t + k - 2) * 384 + d);
    a0 = fmaf(bf2f(v.x), w[(d + 0) * 3 + k], a0);
    a1 = fmaf(bf2f(v.y), w[(d + 1) * 3 + k], a1);
    a2 = fmaf(bf2f(v.z), w[(d + 2) * 3 + k], a2);
    a3 = fmaf(bf2f(v.w), w[(d + 3) * 3 + k], a3);
  }
  ushort4 o;
  o.x = f2bf(silu_f(a0)); o.y = f2bf(silu_f(a1));
  o.z = f2bf(silu_f(a2)); o.w = f2bf(silu_f(a3));
  *(ushort4*)(xm + (size_t)t * DI + d) = o;
}

// ---------------- x_proj MFMA: wave-task = (16-token strip, tile{B,C,dt}) --------------
// Block 256 = 4 independent waves. Grid = TT/16*3/4 = 864.
// tile 0 -> B fp32, tile 1 -> C fp32 (xdbl_bc [TT][32]); tile 2 -> dt bf16 K-padded
// (dtpad [TT][32], cols 12..31 zero).
__global__ __launch_bounds__(256)
void xproj_kernel(const ushort* __restrict__ xmb, const ushort* __restrict__ Wxt,
                  float* __restrict__ xdbl_bc, ushort* __restrict__ dtpad)
{
  const int w = blockIdx.x * 4 + (threadIdx.x >> 6);   // wave-task id, 3456 total
  const int lane = threadIdx.x & 63;
  const int s = w / 3, tile = w % 3;
  const int l16 = lane & 15, quad = lane >> 4;
  const int token = s * 16 + l16;

  f32x4 acc = {0.f, 0.f, 0.f, 0.f};
#pragma unroll
  for (int k0 = 0; k0 < 192; k0 += 32) {
    bf16x8 xf = *(const bf16x8*)(xmb + (size_t)token * DI + k0 + quad * 8);
    bf16x8 wf = *(const bf16x8*)(Wxt + (size_t)(tile * 16 + l16) * 192 + k0 + quad * 8);
    acc = __builtin_amdgcn_mfma_f32_16x16x32_bf16(wf, xf, acc, 0, 0, 0);
  }
  // D: col=l16 (token), row=quad*4+r (n within tile)
  if (tile < 2) {
    *(float4*)(xdbl_bc + (size_t)token * 32 + tile * 16 + quad * 4) =
        make_float4(acc[0], acc[1], acc[2], acc[3]);
  } else {
    // Wxt rows 44..47 are zero so acc==0 for n>=12 automatically
    ushort4 o;
    o.x = f2bf(acc[0]); o.y = f2bf(acc[1]); o.z = f2bf(acc[2]); o.w = f2bf(acc[3]);
    *(ushort4*)(dtpad + (size_t)token * 32 + quad * 4) = o;
    *(ushort4*)(dtpad + (size_t)token * 32 + 16 + quad * 4) = make_ushort4(0, 0, 0, 0);
  }
}

// ---------------- dt_proj MFMA + softplus: wave-task = (strip, colgroup) ----------------
// Block 256 = 4 independent waves. Grid = TT/16*3/4 = 864.
__global__ __launch_bounds__(256)
void dtproj_kernel(const ushort* __restrict__ dtpad, const ushort* __restrict__ Wdtt,
                   const float* __restrict__ bdt, float* __restrict__ dlt)
{
  const int w = blockIdx.x * 4 + (threadIdx.x >> 6);   // 3456 total
  const int lane = threadIdx.x & 63;
  const int s = w / 3, cg = w % 3;                     // colgroup: 64 delta-cols
  const int l16 = lane & 15, quad = lane >> 4;
  const int token = s * 16 + l16;
  const f32x4 z4 = {0.f, 0.f, 0.f, 0.f};

  bf16x8 dtf = *(const bf16x8*)(dtpad + (size_t)token * 32 + quad * 8);
  f32x4 acc[4];
#pragma unroll
  for (int jj = 0; jj < 4; ++jj) {
    bf16x8 wf = *(const bf16x8*)(Wdtt + (size_t)(cg * 64 + jj * 16 + l16) * 32 + quad * 8);
    acc[jj] = __builtin_amdgcn_mfma_f32_16x16x32_bf16(wf, dtf, z4, 0, 0, 0);
  }
#pragma unroll
  for (int jj = 0; jj < 4; ++jj) {
    const int nb = cg * 64 + jj * 16 + quad * 4;
    float4 dv;
    dv.x = softplus_f(acc[jj][0] + bdt[nb + 0]);
    dv.y = softplus_f(acc[jj][1] + bdt[nb + 1]);
    dv.z = softplus_f(acc[jj][2] + bdt[nb + 2]);
    dv.w = softplus_f(acc[jj][3] + bdt[nb + 3]);
    *(float4*)(dlt + (size_t)token * DI + nb) = dv;
  }
}

// ---------------- selective scan: thread = (b, chunk, d), 16 n-states in regs ----------------
__global__ __launch_bounds__(192)
void scan1_kernel(const float* __restrict__ dlt, const ushort* __restrict__ xmb,
                  const float* __restrict__ xdbl_bc, const float* __restrict__ Alog,
                  float* __restrict__ P, float* __restrict__ E)
{
  const int d = threadIdx.x;               // 0..191
  const int g = blockIdx.x % NCHUNK;
  const int b = blockIdx.x / NCHUNK;
  const int t0 = b * LSEQ + g * CHUNK;
  float Av[16];
#pragma unroll
  for (int j = 0; j < 16; ++j) Av[j] = -__expf(Alog[d * 16 + j]);
  float e[16];
#pragma unroll
  for (int j = 0; j < 16; ++j) e[j] = 0.f;
  float sdl = 0.f;
#pragma unroll 2
  for (int l = 0; l < CHUNK; ++l) {
    const int t = t0 + l;
    float dl = dlt[(size_t)t * DI + d];
    float u  = bf2f(xmb[(size_t)t * DI + d]);
    const float4 B0 = *(const float4*)(xdbl_bc + (size_t)t * 32 + 0);
    const float4 B1 = *(const float4*)(xdbl_bc + (size_t)t * 32 + 4);
    const float4 B2 = *(const float4*)(xdbl_bc + (size_t)t * 32 + 8);
    const float4 B3 = *(const float4*)(xdbl_bc + (size_t)t * 32 + 12);
    const float Bv[16] = {B0.x, B0.y, B0.z, B0.w, B1.x, B1.y, B1.z, B1.w,
                          B2.x, B2.y, B2.z, B2.w, B3.x, B3.y, B3.z, B3.w};
    float du = dl * u;
    sdl += dl;
#pragma unroll
    for (int j = 0; j < 16; ++j) {
      float a = __expf(dl * Av[j]);
      e[j] = fmaf(a, e[j], du * Bv[j]);
    }
  }
  size_t base = ((size_t)(b * NCHUNK + g)) * QDN + d * 16;
#pragma unroll
  for (int j = 0; j < 16; ++j) {
    P[base + j] = __expf(Av[j] * sdl);
    E[base + j] = e[j];
  }
}

// level-2a: per super-chunk product/accum over SUP chunks
__global__ __launch_bounds__(256)
void scan2a_kernel(const float* __restrict__ P, const float* __restrict__ E,
                   float* __restrict__ SP, float* __restrict__ SE)
{
  int id = blockIdx.x * 256 + threadIdx.x;  // BATCH*NSUP*QDN = 73728
  int q = id % QDN;
  int s = (id / QDN) % NSUP;
  int b = id / (QDN * NSUP);
  float cp = 1.f, ce = 0.f;
#pragma unroll 4
  for (int c = 0; c < SUP; ++c) {
    size_t idx = ((size_t)(b * NCHUNK + s * SUP + c)) * QDN + q;
    float p = P[idx], e = E[idx];
    ce = fmaf(p, ce, e);
    cp *= p;
  }
  SP[id] = cp; SE[id] = ce;
}

// level-2b: serial scan over NSUP super-chunks
__global__ __launch_bounds__(256)
void scan2b_kernel(const float* __restrict__ SP, const float* __restrict__ SE,
                   float* __restrict__ Hsup)
{
  int id = blockIdx.x * 256 + threadIdx.x;  // BATCH*QDN = 6144
  int q = id % QDN;
  int b = id / QDN;
  float carry = 0.f;
#pragma unroll
  for (int s = 0; s < NSUP; ++s) {
    size_t idx = ((size_t)(b * NSUP + s)) * QDN + q;
    Hsup[idx] = carry;
    carry = fmaf(SP[idx], carry, SE[idx]);
  }
}

// level-2c: expand to per-chunk inbound states
__global__ __launch_bounds__(256)
void scan2c_kernel(const float* __restrict__ P, const float* __restrict__ E,
                   const float* __restrict__ Hsup, float* __restrict__ Hin)
{
  int id = blockIdx.x * 256 + threadIdx.x;  // 73728
  int q = id % QDN;
  int s = (id / QDN) % NSUP;
  int b = id / (QDN * NSUP);
  float h = Hsup[id];
#pragma unroll 4
  for (int c = 0; c < SUP; ++c) {
    size_t idx = ((size_t)(b * NCHUNK + s * SUP + c)) * QDN + q;
    Hin[idx] = h;
    h = fmaf(P[idx], h, E[idx]);
  }
}

// phase3: replay chunk, y = (sum_n h*C + u*D) * silu(z) -> bf16
__global__ __launch_bounds__(192)
void scan3_kernel(const float* __restrict__ dlt, const ushort* __restrict__ xmb,
                  const float* __restrict__ xdbl_bc, const float* __restrict__ Alog,
                  const float* __restrict__ Dv, const ushort* __restrict__ xz1,
                  const float* __restrict__ Hin, ushort* __restrict__ yout)
{
  const int d = threadIdx.x;
  const int g = blockIdx.x % NCHUNK;
  const int b = blockIdx.x / NCHUNK;
  const int t0 = b * LSEQ + g * CHUNK;
  float Av[16];
#pragma unroll
  for (int j = 0; j < 16; ++j) Av[j] = -__expf(Alog[d * 16 + j]);
  const float Dd = Dv[d];
  float h[16];
  {
    size_t hb = ((size_t)(b * NCHUNK + g)) * QDN + d * 16;
#pragma unroll
    for (int j = 0; j < 16; ++j) h[j] = Hin[hb + j];
  }
#pragma unroll 2
  for (int l = 0; l < CHUNK; ++l) {
    const int t = t0 + l;
    float dl = dlt[(size_t)t * DI + d];
    float u  = bf2f(xmb[(size_t)t * DI + d]);
    const float4 B0 = *(const float4*)(xdbl_bc + (size_t)t * 32 + 0);
    const float4 B1 = *(const float4*)(xdbl_bc + (size_t)t * 32 + 4);
    const float4 B2 = *(const float4*)(xdbl_bc + (size_t)t * 32 + 8);
    const float4 B3 = *(const float4*)(xdbl_bc + (size_t)t * 32 + 12);
    const float4 C0 = *(const float4*)(xdbl_bc + (size_t)t * 32 + 16);
    const float4 C1 = *(const float4*)(xdbl_bc + (size_t)t * 32 + 20);
    const float4 C2 = *(const float4*)(xdbl_bc + (size_t)t * 32 + 24);
    const float4 C3 = *(const float4*)(xdbl_bc + (size_t)t * 32 + 28);
    const float Bv[16] = {B0.x, B0.y, B0.z, B0.w, B1.x, B1.y, B1.z, B1.w,
                          B2.x, B2.y, B2.z, B2.w, B3.x, B3.y, B3.z, B3.w};
    const float Cv[16] = {C0.x, C0.y, C0.z, C0.w, C1.x, C1.y, C1.z, C1.w,
                          C2.x, C2.y, C2.z, C2.w, C3.x, C3.y, C3.z, C3.w};
    float du = dl * u;
    float y0 = 0.f, y1 = 0.f, y2 = 0.f, y3 = 0.f;
#pragma unroll
    for (int j = 0; j < 16; ++j) {
      float a = __expf(dl * Av[j]);
      h[j] = fmaf(a, h[j], du * Bv[j]);
      if ((j & 3) == 0) y0 = fmaf(h[j], Cv[j], y0);
      else if ((j & 3) == 1) y1 = fmaf(h[j], Cv[j], y1);
      else if ((j & 3) == 2) y2 = fmaf(h[j], Cv[j], y2);
      else y3 = fmaf(h[j], Cv[j], y3);
    }
    float y = (y0 + y1) + (y2 + y3) + u * Dd;
    float z = bf2f(xz1[(size_t)t * 384 + 192 + d]);
    yout[(size_t)t * DI + d] = f2bf(y * silu_f(z));
  }
}

// ---------------- launch ----------------
extern "C" void kernel_launch(void* const* d_in, const int* in_sizes, int n_in,
                              void* d_out, int out_size, void* d_ws, size_t ws_size,
                              hipStream_t stream)
{
  const float* x         = (const float*)d_in[0];
  const float* norm_w    = (const float*)d_in[1];
  const float* norm_b    = (const float*)d_in[2];
  const float* in_proj_w = (const float*)d_in[3];
  const float* conv2d_w  = (const float*)d_in[4];
  const float* m_in_proj = (const float*)d_in[5];
  const float* m_c1d_w   = (const float*)d_in[6];
  const float* m_c1d_b   = (const float*)d_in[7];
  const float* m_x_proj  = (const float*)d_in[8];
  const float* m_dt_w    = (const float*)d_in[9];
  const float* m_dt_b    = (const float*)d_in[10];
  const float* m_A_log   = (const float*)d_in[11];
  const float* m_D       = (const float*)d_in[12];
  const float* m_out_w   = (const float*)d_in[13];
  const float* out_w     = (const float*)d_in[14];
  float* out = (float*)d_out;

  char* wp = (char*)d_ws;
  auto alloc = [&](size_t bytes) {
    char* r = wp; wp += (bytes + 255) & ~(size_t)255; return r;
  };
  ushort* Wt0    = (ushort*)alloc(36864 * 2);      // [384][96]
  ushort* Wt1    = (ushort*)alloc(73728 * 2);      // [384][192]
  ushort* Wt2    = (ushort*)alloc(36864 * 2);      // [192][192]
  ushort* Wt3    = (ushort*)alloc(24576 * 2);      // [128][192]
  ushort* Wxt    = (ushort*)alloc(9216 * 2);       // [48][192]
  ushort* Wdtt   = (ushort*)alloc(6144 * 2);       // [192][32]
  ushort* xn_bf  = (ushort*)alloc((size_t)TT * 96 * 2);
  ushort* xz0    = (ushort*)alloc((size_t)TT * 384 * 2);   // x_in | gate (bf16)
  ushort* xc_bf  = (ushort*)alloc((size_t)TT * 192 * 2);
  ushort* xz1    = (ushort*)alloc((size_t)TT * 384 * 2);   // xm_pre | z (bf16)
  ushort* xmb_bf = (ushort*)alloc((size_t)TT * 192 * 2);
  ushort* dtpad  = (ushort*)alloc((size_t)TT * 32 * 2);    // dt K-padded bf16
  float*  xdbl_bc= (float*)alloc((size_t)TT * 32 * 4);     // B | C (fp32)
  float*  dlt    = (float*)alloc((size_t)TT * 192 * 4);
  float*  Pb     = (float*)alloc((size_t)BATCH * NCHUNK * QDN * 4);
  float*  Eb     = (float*)alloc((size_t)BATCH * NCHUNK * QDN * 4);
  float*  Hin    = (float*)alloc((size_t)BATCH * NCHUNK * QDN * 4);
  float*  SPb    = (float*)alloc((size_t)BATCH * NSUP * QDN * 4);
  float*  SEb    = (float*)alloc((size_t)BATCH * NSUP * QDN * 4);
  float*  Hsup   = (float*)alloc((size_t)BATCH * NSUP * QDN * 4);
  ushort* yfin   = (ushort*)alloc((size_t)TT * 192 * 2);
  ushort* yg     = (ushort*)alloc((size_t)TT * 192 * 2);

  // 0. weight cast/transpose/permute
  castw_kernel<<<732, 256, 0, stream>>>(in_proj_w, m_in_proj, m_out_w, out_w,
                                        m_x_proj, m_dt_w,
                                        Wt0, Wt1, Wt2, Wt3, Wxt, Wdtt);
  // 1. LayerNorm -> bf16
  ln_kernel<<<TT / 4, 256, 0, stream>>>(x, norm_w, norm_b, xn_bf);
  // 2. in_proj (MFMA): -> xz0 bf16 (18432x384)
  mfma_gemm_kernel<0, 1><<<dim3(TT / 128, 6), 256, 0, stream>>>(
      xn_bf, 96, Wt0, 96, xz0, 384, 384, 96, nullptr, 0);
  // 3. dw 3x3 conv + SiLU -> xc bf16
  conv2d_silu_kernel<<<TT * 48 / 256, 256, 0, stream>>>(xz0, conv2d_w, xc_bf);
  // 4. m_in_proj (MFMA): -> xz1 bf16 (18432x384)
  mfma_gemm_kernel<0, 1><<<dim3(TT / 128, 6), 256, 0, stream>>>(
      xc_bf, 192, Wt1, 192, xz1, 384, 384, 192, nullptr, 0);
  // 5a. causal conv1d + bias + SiLU -> xmb bf16
  conv1d_silu_kernel<<<TT * 48 / 256, 256, 0, stream>>>(xz1, m_c1d_w, m_c1d_b, xmb_bf);
  // 5b. x_proj (MFMA, wave-per-strip-tile) -> xdbl_bc fp32, dtpad bf16
  xproj_kernel<<<TT / 16 * 3 / 4, 256, 0, stream>>>(xmb_bf, Wxt, xdbl_bc, dtpad);
  // 5c. dt_proj (MFMA) + softplus -> dlt fp32
  dtproj_kernel<<<TT / 16 * 3 / 4, 256, 0, stream>>>(dtpad, Wdtt, m_dt_b, dlt);
  // 6. chunked selective scan
  scan1_kernel<<<BATCH * NCHUNK, 192, 0, stream>>>(dlt, xmb_bf, xdbl_bc, m_A_log, Pb, Eb);
  scan2a_kernel<<<BATCH * NSUP * QDN / 256, 256, 0, stream>>>(Pb, Eb, SPb, SEb);
  scan2b_kernel<<<BATCH * QDN / 256, 256, 0, stream>>>(SPb, SEb, Hsup);
  scan2c_kernel<<<BATCH * NSUP * QDN / 256, 256, 0, stream>>>(Pb, Eb, Hsup, Hin);
  scan3_kernel<<<BATCH * NCHUNK, 192, 0, stream>>>(dlt, xmb_bf, xdbl_bc, m_A_log, m_D, xz1, Hin, yfin);
  // 7. m_out_proj (MFMA) with silu(gate) epilogue -> yg bf16
  mfma_gemm_kernel<1, 1><<<dim3(TT / 128, 3), 256, 0, stream>>>(
      yfin, 192, Wt2, 192, yg, 192, 192, 192, xz0 + 192, 384);
  // 8. out_proj (MFMA) with residual epilogue -> out fp32
  mfma_gemm_kernel<2, 0><<<dim3(TT / 128, 2), 256, 0, stream>>>(
      yg, 192, Wt3, 192, out, 96, 96, 192, x, 96);
}